// Round 19
// baseline (129.810 us; speedup 1.0000x reference)
//
#include <hip/hip_runtime.h>
#include <hip/hip_bf16.h>

// ---------------------------------------------------------------------------
// BehaviorSpecificPFF: token-routed 4-expert FFN.
//   y[tok] = relu(x[tok] @ W1[g] + B1[g]) @ W2[g] + B2[g],  g = b_seq[tok]-1
//   b_seq==0 -> zeros.
// Round 19: best-of-each combo. GEMM1 = r18's pinned distance-3 frag-direct
// K-loop (~35us, works because 1664 blocks give ~5/CU TLP on top of the
// register pipeline) + r17's epilogue (Hp in OLD packed order). GEMM2 =
// r17's LDS+T4 counted-pipeline kernel byte-for-byte (51-53us; frag-direct
// regressed it to 63.5us -- only 416 blocks = 1.6/CU, not enough TLP).
// W1p frag-order, W2p old-order (template<FRAG> transpose).
// ---------------------------------------------------------------------------

typedef short s16x8 __attribute__((ext_vector_type(8)));
typedef float f32x4 __attribute__((ext_vector_type(4)));

#define NTOK   16384
#define HDIM   512
#define FDIM   2048
#define NEXP   4
#define MAXMT  132   // worst-case total 128-row m-tiles (4 experts)
#define SB()   __builtin_amdgcn_sched_barrier(0)

// ---- header layout (ints) in ws ----
// [0..3] counts  [4..7] cursors  [8..12] token offsets ([12]=total)
// [13..17] gemm1 tile bases, mt-base = hdr[13+g]>>4 ([17]=total)
// [18..22] gemm2 tile bases, mt-base = hdr[18+g]>>2

__global__ void k_init(const int4* __restrict__ b4,
                       const int* __restrict__ b_seq,
                       float4* __restrict__ out, int n4,
                       int* __restrict__ hdr) {
  if (blockIdx.x == 0) {   // fused count+scan
    __shared__ int cnt[4];
    const int t = threadIdx.x;
    if (t < 4) cnt[t] = 0;
    __syncthreads();
    int c0 = 0, c1 = 0, c2 = 0, c3 = 0;
    for (int i = t; i < NTOK / 4; i += 256) {
      int4 v = b4[i];
      c0 += (v.x == 1) + (v.y == 1) + (v.z == 1) + (v.w == 1);
      c1 += (v.x == 2) + (v.y == 2) + (v.z == 2) + (v.w == 2);
      c2 += (v.x == 3) + (v.y == 3) + (v.z == 3) + (v.w == 3);
      c3 += (v.x == 4) + (v.y == 4) + (v.z == 4) + (v.w == 4);
    }
    if (c0) atomicAdd(&cnt[0], c0);
    if (c1) atomicAdd(&cnt[1], c1);
    if (c2) atomicAdd(&cnt[2], c2);
    if (c3) atomicAdd(&cnt[3], c3);
    __syncthreads();
    if (t == 0) {
      int off = 0, b1 = 0, b2 = 0;
      for (int g = 0; g < 4; ++g) {
        int c = cnt[g];
        hdr[g] = c;
        hdr[8 + g] = off;
        hdr[4 + g] = off;   // cursor
        hdr[13 + g] = b1;
        hdr[18 + g] = b2;
        int mt = (c + 127) >> 7;
        off += c;
        b1 += mt * 16;
        b2 += mt * 4;
      }
      hdr[12] = off; hdr[17] = b1; hdr[22] = b2;
    }
  }
  float4 z; z.x = z.y = z.z = z.w = 0.f;
  for (int i = blockIdx.x * blockDim.x + threadIdx.x; i < n4;
       i += gridDim.x * blockDim.x) {
    // non-pad out rows are fully rewritten by GEMM2 every call; only padding
    // rows need zeros (out float4-row token = i>>7).
    if (b_seq[i >> 7] == 0) out[i] = z;
  }
}

// LDS-aggregated fill: one global atomic per (block, expert).
__global__ void k_fill(const int* __restrict__ b_seq, int* __restrict__ hdr,
                       int* __restrict__ perm) {
  __shared__ int lcnt[4], base[4];
  const int tid = threadIdx.x;
  if (tid < 4) lcnt[tid] = 0;
  __syncthreads();
  const int i = blockIdx.x * 256 + tid;
  const int g = b_seq[i];
  int r = -1;
  if (g > 0) r = atomicAdd(&lcnt[g - 1], 1);
  __syncthreads();
  if (tid < 4) {
    int c = lcnt[tid];
    base[tid] = c ? atomicAdd(&hdr[4 + tid], c) : 0;
  }
  __syncthreads();
  if (g > 0) perm[base[g - 1] + r] = i;
}

// Gather + convert x into FRAGMENT-ORDER A tiles:
//   xa[mtile][ks][kk][rb][lane]: lane l holds row rb*16+(l&15),
//   k = ks*64 + kk*32 + (l>>4)*8 .. +7 (16B per lane-slot).
// One block per (mtile, ks). OOB rows zero-filled.
__global__ __launch_bounds__(256)
void k_pack_a(const float* __restrict__ x, const int* __restrict__ hdr,
              const int* __restrict__ perm, __hip_bfloat16* __restrict__ xa) {
  const int nmt = hdr[17] >> 4;
  const int b = blockIdx.x >> 3, ks = blockIdx.x & 7;
  if (b >= nmt) return;
  int g = 0;
  while ((hdr[13 + g + 1] >> 4) <= b) ++g;
  const int mt = b - (hdr[13 + g] >> 4);
  const int off = hdr[8 + g], cnt = hdr[g];
  int nrows = cnt - (mt << 7);
  nrows = nrows > 128 ? 128 : nrows;
  const int t = threadIdx.x;
  const int kk = t >> 7, rb = (t >> 4) & 7, l0 = (t & 15) << 2;
  __hip_bfloat16* dst = xa + ((size_t)b << 16) + (ks << 13) +
                        ((((kk << 3) + rb) << 6) + l0) * 8;
#pragma unroll
  for (int i = 0; i < 4; ++i) {
    const int l = l0 + i;
    const int row = (rb << 4) + (l & 15);
    union { __hip_bfloat16 b16[8]; s16x8 v; } u;
    if (row < nrows) {
      const float* src = x + (size_t)perm[off + (mt << 7) + row] * HDIM +
                         (ks << 6) + (kk << 5) + ((l >> 4) << 3);
      float4 v0 = *(const float4*)(src);
      float4 v1 = *(const float4*)(src + 4);
      u.b16[0] = __float2bfloat16(v0.x); u.b16[1] = __float2bfloat16(v0.y);
      u.b16[2] = __float2bfloat16(v0.z); u.b16[3] = __float2bfloat16(v0.w);
      u.b16[4] = __float2bfloat16(v1.x); u.b16[5] = __float2bfloat16(v1.y);
      u.b16[6] = __float2bfloat16(v1.z); u.b16[7] = __float2bfloat16(v1.w);
    } else {
      const s16x8 zz = {0, 0, 0, 0, 0, 0, 0, 0};
      u.v = zz;
    }
    *(s16x8*)(dst + i * 8) = u.v;
  }
}

// Transpose+convert W into packed K-step tiles.
// FRAG=true  (W1p): fragment order [tile][ks][kk][rb][lane] (GEMM1 direct).
// FRAG=false (W2p): old order [tile][ks][row128][k64] (GEMM2 LDS path).
// grid (C/64, R/64, NEXP), block 256.
template <bool FRAG>
__global__ void k_transpose_cvt(const float* __restrict__ src,
                                __hip_bfloat16* __restrict__ dst, int R, int C) {
  __shared__ float tile[64][69];   // pad 69: conflict-free col reads
  const int g = blockIdx.z;
  const float* S = src + (size_t)g * R * C;
  const int c0 = blockIdx.x << 6, r0 = blockIdx.y << 6;
  const int t = threadIdx.x;
  const int lr = t >> 4, lc = (t & 15) << 2;
#pragma unroll
  for (int p = 0; p < 4; ++p) {
    float4 v = *(const float4*)(S + (size_t)(r0 + lr + p * 16) * C + c0 + lc);
    float* tr = &tile[lr + p * 16][lc];
    tr[0] = v.x; tr[1] = v.y; tr[2] = v.z; tr[3] = v.w;
  }
  __syncthreads();
  const int c = t >> 2, rq = t & 3;
  union { __hip_bfloat16 b[8]; s16x8 v; } u0, u1;
#pragma unroll
  for (int j = 0; j < 8; ++j) {
    u0.b[j] = __float2bfloat16(tile[rq * 16 + j][c]);
    u1.b[j] = __float2bfloat16(tile[rq * 16 + 8 + j][c]);
  }
  const int rI = c0 + c, kI = r0 + rq * 16;
  const int tl = g * (C >> 7) + (rI >> 7);
  if constexpr (!FRAG) {
    const size_t idx = (((size_t)tl * (R >> 6) + (kI >> 6)) << 13) +
                       ((rI & 127) << 6) + (kI & 63);
    *(s16x8*)(dst + idx) = u0.v;
    *(s16x8*)(dst + idx + 8) = u1.v;
  } else {
    const int ks = kI >> 6, kk = (kI >> 5) & 1, lq0 = (kI >> 3) & 3;
    const int rb = (rI & 127) >> 4;
    const size_t base = (((size_t)tl * (R >> 6) + ks) << 13) +
                        ((((kk << 3) + rb) << 6) + (lq0 << 4) + (rI & 15)) * 8;
    *(s16x8*)(dst + base) = u0.v;          // lane lq0*16 + l15
    *(s16x8*)(dst + base + 128) = u1.v;    // lane (lq0+1)*16 + l15
  }
}

__device__ __forceinline__ f32x4 mfma16(s16x8 a, s16x8 b, f32x4 c) {
  asm("v_mfma_f32_16x16x32_bf16 %0, %1, %2, %0" : "+v"(c) : "v"(a), "v"(b));
  return c;
}

__device__ __forceinline__ void gload16(const void* g, void* lds) {
  __builtin_amdgcn_global_load_lds(
      (const __attribute__((address_space(1))) unsigned int*)g,
      (__attribute__((address_space(3))) unsigned int*)lds, 16, 0, 0);
}

// GEMM1 (LDS-free K-loop, PINNED distance-3 pipeline): 128x128 tile, BK=64,
// 4 waves (2m x 2n). Fragment-order operands; each fragment = 1 contiguous
// 1KB load. LD(0..2); loop { LD(ph+3); SB; MM(ph); SB; } with 4 named sets.
// LDS only for the C-stage epilogue (relu+bias -> Hp OLD packed order).
__global__ __launch_bounds__(256)
void k_gemm1(const int* __restrict__ hdr,
             const __hip_bfloat16* __restrict__ Ap,
             const __hip_bfloat16* __restrict__ Bp,
             const float* __restrict__ bias,
             __hip_bfloat16* __restrict__ Hout) {
  constexpr int NS = 8, NT = 16, NPH = 2 * NS;
  const int* tb = hdr + 13;
  const int total = tb[4];

  __shared__ __align__(16) char LDS[34816];   // C-stage only (128 x 272B)

  const int idx = blockIdx.x;
  if (idx >= total) return;
  const int qc = total >> 3, rc = total & 7;
  const int xcd = idx & 7;
  const int cbase = (xcd < rc) ? xcd * (qc + 1) : rc * (qc + 1) + (xcd - rc) * qc;
  const int w = cbase + (idx >> 3);

  const int tid = threadIdx.x, lane = tid & 63, wv = tid >> 6;
  const int wm = (wv >> 1) << 6, wn = (wv & 1) << 6;
  const int l15 = lane & 15, lq = lane >> 4;

  int g = 0;
  while (tb[g + 1] <= w) ++g;
  const int local = w - tb[g];
  const int mt = local / NT, nt = local % NT;
  const int cnt = hdr[g];
  int nrows = cnt - (mt << 7);
  nrows = nrows > 128 ? 128 : nrows;

  const int amt = (hdr[13 + g] >> 4) + mt;
  const __hip_bfloat16* aF = Ap + (((size_t)amt * NS) << 13) +
                             (((wv >> 1) << 2) << 9) + lane * 8;
  const __hip_bfloat16* bF = Bp + (((size_t)(g * NT + nt) * NS) << 13) +
                             (((wv & 1) << 2) << 9) + lane * 8;

  f32x4 acc[4][4];
  const f32x4 fz = {0.f, 0.f, 0.f, 0.f};
#pragma unroll
  for (int m = 0; m < 4; ++m)
#pragma unroll
    for (int n = 0; n < 4; ++n) acc[m][n] = fz;

  s16x8 a0[4], b0[4], a1[4], b1[4], a2[4], b2[4], a3[4], b3[4];
  auto LD = [&](int ph, s16x8* a, s16x8* b) {
    const size_t o = (size_t)ph << 12;
#pragma unroll
    for (int i = 0; i < 4; ++i) {
      a[i] = *(const s16x8*)(aF + o + (i << 9));
      b[i] = *(const s16x8*)(bF + o + (i << 9));
    }
  };
  auto MM = [&](s16x8* a, s16x8* b) {
    __builtin_amdgcn_s_setprio(1);
#pragma unroll
    for (int m = 0; m < 4; ++m)
#pragma unroll
      for (int n = 0; n < 4; ++n)
        acc[m][n] = mfma16(a[m], b[n], acc[m][n]);
    __builtin_amdgcn_s_setprio(0);
  };

  LD(0, a0, b0); SB();
  LD(1, a1, b1); SB();
  LD(2, a2, b2); SB();
#pragma unroll
  for (int ph = 0; ph < NPH; ph += 4) {
    if (ph + 3 < NPH) LD(ph + 3, a3, b3);
    SB(); MM(a0, b0); SB();
    if (ph + 4 < NPH) LD(ph + 4, a0, b0);
    SB(); MM(a1, b1); SB();
    if (ph + 5 < NPH) LD(ph + 5, a1, b1);
    SB(); MM(a2, b2); SB();
    if (ph + 6 < NPH) LD(ph + 6, a2, b2);
    SB(); MM(a3, b3); SB();
  }
  asm volatile("s_nop 7\ns_nop 7\ns_nop 7");    // MFMA->VALU hazard guard

  // epilogue (r17-proven): relu+bias via LDS C-stage (stride 272), then
  // 128B stores into Hp's OLD packed layout (GEMM2 LDS path consumes it).
  const int rq = lq << 2;
#pragma unroll
  for (int n = 0; n < 4; ++n) {
    const int col = wn + (n << 4) + l15;
    const float bv = bias[g * FDIM + (nt << 7) + col];
#pragma unroll
    for (int m = 0; m < 4; ++m)
#pragma unroll
      for (int j = 0; j < 4; ++j) {
        const int row = wm + (m << 4) + rq + j;
        float v = acc[m][n][j] + bv;
        v = v > 0.f ? v : 0.f;
        *(__hip_bfloat16*)(LDS + row * 272 + col * 2) = __float2bfloat16(v);
      }
  }
  __syncthreads();
  const int r = tid >> 1, hf = tid & 1;
  if (r < nrows) {
    const char* src = LDS + r * 272 + hf * 128;
    const size_t tIdx =
        ((size_t)((hdr[18 + g] >> 2) + mt) * 32 + (nt << 1) + hf);
    char* dst = (char*)(Hout + (tIdx << 13) + r * 64);
#pragma unroll
    for (int q = 0; q < 8; ++q)
      *(s16x8*)(dst + q * 16) = *(const s16x8*)(src + q * 16);
  }
}

// GEMM2: r17-verbatim (128x128, BK=64, LDS + T4 depth-2 counted pipeline).
// A = Hp packed old-order (K=2048), B = W2p; +bias; fp32 scatter via perm.
__global__ __launch_bounds__(256, 2)
void k_gemm2(const int* __restrict__ hdr, const int* __restrict__ perm,
             const __hip_bfloat16* __restrict__ Ap,
             const __hip_bfloat16* __restrict__ Bp,
             const float* __restrict__ bias, float* __restrict__ Yout) {
  constexpr int NS = 32;
  constexpr int NT = 4;
  constexpr int NF = HDIM;
  const int* tb = hdr + 18;
  const int total = tb[4];

  __shared__ __align__(16) char LDS[65536];
  char* As = LDS;
  char* Bs = LDS + 32768;

  const int idx = blockIdx.x;
  if (idx >= total) return;
  const int qc = total >> 3, rc = total & 7;
  const int xcd = idx & 7;
  const int cbase = (xcd < rc) ? xcd * (qc + 1) : rc * (qc + 1) + (xcd - rc) * qc;
  const int w = cbase + (idx >> 3);

  const int tid = threadIdx.x, lane = tid & 63, wv = tid >> 6;
  const int wm = (wv >> 1) << 6, wn = (wv & 1) << 6;
  const int l15 = lane & 15, lq = lane >> 4;
  const int rsub = lane >> 3, c8 = lane & 7;

  int g = 0;
  while (tb[g + 1] <= w) ++g;
  const int local = w - tb[g];
  const int mt = local / NT, nt = local % NT;
  const int cnt = hdr[g], off = hdr[8 + g];
  int nrows = cnt - (mt << 7);
  nrows = nrows > 128 ? 128 : nrows;

  const int amt = (hdr[18 + g] >> 2) + mt;
  const int lelem = ((wv << 5) + rsub) * 64 + ((c8 ^ rsub) << 3);
  const __hip_bfloat16* abase = Ap + (((size_t)amt * NS) << 13) + lelem;
  const __hip_bfloat16* bbase =
      Bp + (((size_t)(g * NT + nt) * NS) << 13) + lelem;

  f32x4 acc[4][4];
  const f32x4 fz = {0.f, 0.f, 0.f, 0.f};
#pragma unroll
  for (int m = 0; m < 4; ++m)
#pragma unroll
    for (int n = 0; n < 4; ++n) acc[m][n] = fz;

  auto STAGE = [&](int s, int p) {
    const size_t so = (size_t)s << 13;
    char* Ad = As + (p << 14) + (wv << 12);
    char* Bd = Bs + (p << 14) + (wv << 12);
#pragma unroll
    for (int i = 0; i < 4; ++i) {
      gload16(abase + so + (i << 9), Ad + (i << 10));
      gload16(bbase + so + (i << 9), Bd + (i << 10));
    }
  };
  auto COMPUTE = [&](int p) {
    const char* Ab = As + (p << 14);
    const char* Bb = Bs + (p << 14);
#pragma unroll
    for (int kk = 0; kk < 2; ++kk) {
      const int kb = (kk << 6) + (lq << 4);
      s16x8 a[4], b[4];
#pragma unroll
      for (int m = 0; m < 4; ++m) {
        const int row = wm + (m << 4) + l15;
        a[m] = *(const s16x8*)(Ab + (row << 7) + (kb ^ ((row & 7) << 4)));
      }
#pragma unroll
      for (int n = 0; n < 4; ++n) {
        const int row = wn + (n << 4) + l15;
        b[n] = *(const s16x8*)(Bb + (row << 7) + (kb ^ ((row & 7) << 4)));
      }
      __builtin_amdgcn_s_setprio(1);
#pragma unroll
      for (int m = 0; m < 4; ++m)
#pragma unroll
        for (int n = 0; n < 4; ++n)
          acc[m][n] = mfma16(a[m], b[n], acc[m][n]);
      __builtin_amdgcn_s_setprio(0);
    }
  };

  STAGE(0, 0);
  for (int s = 0; s < NS; ++s) {
    const int p = s & 1;
    if (s + 1 < NS) {
      STAGE(s + 1, p ^ 1);
      asm volatile("s_waitcnt vmcnt(8)" ::: "memory");
    } else {
      asm volatile("s_waitcnt vmcnt(0)" ::: "memory");
    }
    __builtin_amdgcn_s_barrier();
    asm volatile("" ::: "memory");
    COMPUTE(p);
    asm volatile("" ::: "memory");
    __builtin_amdgcn_s_barrier();
    asm volatile("" ::: "memory");
  }
  asm volatile("s_nop 7\ns_nop 7\ns_nop 7");

  const int rq = lq << 2;
#pragma unroll
  for (int n = 0; n < 4; ++n) {
    const int ncol = (nt << 7) + wn + (n << 4) + l15;
    const float bv = bias[g * NF + ncol];
#pragma unroll
    for (int m = 0; m < 4; ++m)
#pragma unroll
      for (int j = 0; j < 4; ++j) {
        const int rl = wm + (m << 4) + rq + j;
        if (rl < nrows) {
          const int tok = perm[off + (mt << 7) + rl];
          Yout[((size_t)tok << 9) + ncol] = acc[m][n][j] + bv;
        }
      }
  }
}

extern "C" void kernel_launch(void* const* d_in, const int* in_sizes, int n_in,
                              void* d_out, int out_size, void* d_ws,
                              size_t ws_size, hipStream_t stream) {
  const float* x    = (const float*)d_in[0];
  const int* b_seq  = (const int*)d_in[1];
  const float* W1   = (const float*)d_in[2];
  const float* B1   = (const float*)d_in[3];
  const float* W2   = (const float*)d_in[4];
  const float* B2   = (const float*)d_in[5];
  float* out        = (float*)d_out;

  char* ws = (char*)d_ws;
  int* hdr  = (int*)ws;                          // 1 KB header
  int* perm = (int*)(ws + 1024);                 // 64 KB
  __hip_bfloat16* xa  = (__hip_bfloat16*)(ws + 66560);   // frag order
  __hip_bfloat16* W1p = xa + (size_t)MAXMT * 8 * 8192;   // frag order
  __hip_bfloat16* W2p = W1p + (size_t)NEXP * FDIM * HDIM;// old packed order
  __hip_bfloat16* Hp  = W2p + (size_t)NEXP * HDIM * FDIM;// old packed order

  const int n4 = NTOK * HDIM / 4;

  k_init<<<2048, 256, 0, stream>>>((const int4*)b_seq, b_seq, (float4*)out,
                                   n4, hdr);
  k_fill<<<NTOK / 256, 256, 0, stream>>>(b_seq, hdr, perm);
  k_pack_a<<<MAXMT * 8, 256, 0, stream>>>(x, hdr, perm, xa);
  k_transpose_cvt<true><<<dim3(FDIM / 64, HDIM / 64, NEXP), 256, 0, stream>>>(
      W1, W1p, HDIM, FDIM);
  k_transpose_cvt<false><<<dim3(HDIM / 64, FDIM / 64, NEXP), 256, 0, stream>>>(
      W2, W2p, FDIM, HDIM);
  // grids cover worst-case tile counts; blocks past the actual total exit
  k_gemm1<<<2112, 256, 0, stream>>>(hdr, xa, W1p, B1, Hp);
  k_gemm2<<<528, 256, 0, stream>>>(hdr, perm, Hp, W2p, B2, out);
}

// Round 20
// 128.159 us; speedup vs baseline: 1.0129x; 1.0129x over previous
//
#include <hip/hip_runtime.h>
#include <hip/hip_bf16.h>

// ---------------------------------------------------------------------------
// BehaviorSpecificPFF: token-routed 4-expert FFN.
//   y[tok] = relu(x[tok] @ W1[g] + B1[g]) @ W2[g] + B2[g],  g = b_seq[tok]-1
//   b_seq==0 -> zeros.
// Round 20: r19 GEMMs untouched (GEMM1 = pinned distance-3 frag-direct,
// ~35-40us; GEMM2 = LDS+T4 counted depth-2, ~53us -- each proven best for
// its block-count regime). Prep trim only: the two W-transposes fused into
// ONE launch (flat 2048-block grid, runtime path decode), k_init grid
// halved. 7 -> 6 launches.
// ---------------------------------------------------------------------------

typedef short s16x8 __attribute__((ext_vector_type(8)));
typedef float f32x4 __attribute__((ext_vector_type(4)));

#define NTOK   16384
#define HDIM   512
#define FDIM   2048
#define NEXP   4
#define MAXMT  132   // worst-case total 128-row m-tiles (4 experts)
#define SB()   __builtin_amdgcn_sched_barrier(0)

// ---- header layout (ints) in ws ----
// [0..3] counts  [4..7] cursors  [8..12] token offsets ([12]=total)
// [13..17] gemm1 tile bases, mt-base = hdr[13+g]>>4 ([17]=total)
// [18..22] gemm2 tile bases, mt-base = hdr[18+g]>>2

__global__ void k_init(const int4* __restrict__ b4,
                       const int* __restrict__ b_seq,
                       float4* __restrict__ out, int n4,
                       int* __restrict__ hdr) {
  if (blockIdx.x == 0) {   // fused count+scan
    __shared__ int cnt[4];
    const int t = threadIdx.x;
    if (t < 4) cnt[t] = 0;
    __syncthreads();
    int c0 = 0, c1 = 0, c2 = 0, c3 = 0;
    for (int i = t; i < NTOK / 4; i += 256) {
      int4 v = b4[i];
      c0 += (v.x == 1) + (v.y == 1) + (v.z == 1) + (v.w == 1);
      c1 += (v.x == 2) + (v.y == 2) + (v.z == 2) + (v.w == 2);
      c2 += (v.x == 3) + (v.y == 3) + (v.z == 3) + (v.w == 3);
      c3 += (v.x == 4) + (v.y == 4) + (v.z == 4) + (v.w == 4);
    }
    if (c0) atomicAdd(&cnt[0], c0);
    if (c1) atomicAdd(&cnt[1], c1);
    if (c2) atomicAdd(&cnt[2], c2);
    if (c3) atomicAdd(&cnt[3], c3);
    __syncthreads();
    if (t == 0) {
      int off = 0, b1 = 0, b2 = 0;
      for (int g = 0; g < 4; ++g) {
        int c = cnt[g];
        hdr[g] = c;
        hdr[8 + g] = off;
        hdr[4 + g] = off;   // cursor
        hdr[13 + g] = b1;
        hdr[18 + g] = b2;
        int mt = (c + 127) >> 7;
        off += c;
        b1 += mt * 16;
        b2 += mt * 4;
      }
      hdr[12] = off; hdr[17] = b1; hdr[22] = b2;
    }
  }
  float4 z; z.x = z.y = z.z = z.w = 0.f;
  for (int i = blockIdx.x * blockDim.x + threadIdx.x; i < n4;
       i += gridDim.x * blockDim.x) {
    // non-pad out rows are fully rewritten by GEMM2 every call; only padding
    // rows need zeros (out float4-row token = i>>7).
    if (b_seq[i >> 7] == 0) out[i] = z;
  }
}

// LDS-aggregated fill: one global atomic per (block, expert).
__global__ void k_fill(const int* __restrict__ b_seq, int* __restrict__ hdr,
                       int* __restrict__ perm) {
  __shared__ int lcnt[4], base[4];
  const int tid = threadIdx.x;
  if (tid < 4) lcnt[tid] = 0;
  __syncthreads();
  const int i = blockIdx.x * 256 + tid;
  const int g = b_seq[i];
  int r = -1;
  if (g > 0) r = atomicAdd(&lcnt[g - 1], 1);
  __syncthreads();
  if (tid < 4) {
    int c = lcnt[tid];
    base[tid] = c ? atomicAdd(&hdr[4 + tid], c) : 0;
  }
  __syncthreads();
  if (g > 0) perm[base[g - 1] + r] = i;
}

// Gather + convert x into FRAGMENT-ORDER A tiles:
//   xa[mtile][ks][kk][rb][lane]: lane l holds row rb*16+(l&15),
//   k = ks*64 + kk*32 + (l>>4)*8 .. +7 (16B per lane-slot).
// One block per (mtile, ks). OOB rows zero-filled.
__global__ __launch_bounds__(256)
void k_pack_a(const float* __restrict__ x, const int* __restrict__ hdr,
              const int* __restrict__ perm, __hip_bfloat16* __restrict__ xa) {
  const int nmt = hdr[17] >> 4;
  const int b = blockIdx.x >> 3, ks = blockIdx.x & 7;
  if (b >= nmt) return;
  int g = 0;
  while ((hdr[13 + g + 1] >> 4) <= b) ++g;
  const int mt = b - (hdr[13 + g] >> 4);
  const int off = hdr[8 + g], cnt = hdr[g];
  int nrows = cnt - (mt << 7);
  nrows = nrows > 128 ? 128 : nrows;
  const int t = threadIdx.x;
  const int kk = t >> 7, rb = (t >> 4) & 7, l0 = (t & 15) << 2;
  __hip_bfloat16* dst = xa + ((size_t)b << 16) + (ks << 13) +
                        ((((kk << 3) + rb) << 6) + l0) * 8;
#pragma unroll
  for (int i = 0; i < 4; ++i) {
    const int l = l0 + i;
    const int row = (rb << 4) + (l & 15);
    union { __hip_bfloat16 b16[8]; s16x8 v; } u;
    if (row < nrows) {
      const float* src = x + (size_t)perm[off + (mt << 7) + row] * HDIM +
                         (ks << 6) + (kk << 5) + ((l >> 4) << 3);
      float4 v0 = *(const float4*)(src);
      float4 v1 = *(const float4*)(src + 4);
      u.b16[0] = __float2bfloat16(v0.x); u.b16[1] = __float2bfloat16(v0.y);
      u.b16[2] = __float2bfloat16(v0.z); u.b16[3] = __float2bfloat16(v0.w);
      u.b16[4] = __float2bfloat16(v1.x); u.b16[5] = __float2bfloat16(v1.y);
      u.b16[6] = __float2bfloat16(v1.z); u.b16[7] = __float2bfloat16(v1.w);
    } else {
      const s16x8 zz = {0, 0, 0, 0, 0, 0, 0, 0};
      u.v = zz;
    }
    *(s16x8*)(dst + i * 8) = u.v;
  }
}

// Fused W1+W2 transpose/convert (one launch, 2048 blocks).
// Blocks [0,1024): W1 (R=HDIM, C=FDIM) -> W1p in FRAGMENT order.
// Blocks [1024,2048): W2 (R=FDIM, C=HDIM) -> W2p in OLD packed order.
__global__ __launch_bounds__(256)
void k_transpose_both(const float* __restrict__ W1,
                      __hip_bfloat16* __restrict__ W1p,
                      const float* __restrict__ W2,
                      __hip_bfloat16* __restrict__ W2p) {
  __shared__ float tile[64][69];   // pad 69: conflict-free col reads
  const bool first = blockIdx.x < 1024;
  const int id = first ? blockIdx.x : blockIdx.x - 1024;
  const int R = first ? HDIM : FDIM;
  const int C = first ? FDIM : HDIM;
  const int nbx = C >> 6, nby = R >> 6;
  const int bx = id % nbx, rest = id / nbx;
  const int by = rest % nby, g = rest / nby;
  const float* S = (first ? W1 : W2) + (size_t)g * R * C;
  __hip_bfloat16* dst = first ? W1p : W2p;
  const int c0 = bx << 6, r0 = by << 6;
  const int t = threadIdx.x;
  const int lr = t >> 4, lc = (t & 15) << 2;
#pragma unroll
  for (int p = 0; p < 4; ++p) {
    float4 v = *(const float4*)(S + (size_t)(r0 + lr + p * 16) * C + c0 + lc);
    float* tr = &tile[lr + p * 16][lc];
    tr[0] = v.x; tr[1] = v.y; tr[2] = v.z; tr[3] = v.w;
  }
  __syncthreads();
  const int c = t >> 2, rq = t & 3;
  union { __hip_bfloat16 b[8]; s16x8 v; } u0, u1;
#pragma unroll
  for (int j = 0; j < 8; ++j) {
    u0.b[j] = __float2bfloat16(tile[rq * 16 + j][c]);
    u1.b[j] = __float2bfloat16(tile[rq * 16 + 8 + j][c]);
  }
  const int rI = c0 + c, kI = r0 + rq * 16;
  const int tl = g * (C >> 7) + (rI >> 7);
  if (!first) {
    // old packed order [tile][ks][row128][k64]
    const size_t idx = (((size_t)tl * (R >> 6) + (kI >> 6)) << 13) +
                       ((rI & 127) << 6) + (kI & 63);
    *(s16x8*)(dst + idx) = u0.v;
    *(s16x8*)(dst + idx + 8) = u1.v;
  } else {
    // fragment order [tile][ks][kk][rb][lane]
    const int ks = kI >> 6, kk = (kI >> 5) & 1, lq0 = (kI >> 3) & 3;
    const int rb = (rI & 127) >> 4;
    const size_t base = (((size_t)tl * (R >> 6) + ks) << 13) +
                        ((((kk << 3) + rb) << 6) + (lq0 << 4) + (rI & 15)) * 8;
    *(s16x8*)(dst + base) = u0.v;          // lane lq0*16 + l15
    *(s16x8*)(dst + base + 128) = u1.v;    // lane (lq0+1)*16 + l15
  }
}

__device__ __forceinline__ f32x4 mfma16(s16x8 a, s16x8 b, f32x4 c) {
  asm("v_mfma_f32_16x16x32_bf16 %0, %1, %2, %0" : "+v"(c) : "v"(a), "v"(b));
  return c;
}

__device__ __forceinline__ void gload16(const void* g, void* lds) {
  __builtin_amdgcn_global_load_lds(
      (const __attribute__((address_space(1))) unsigned int*)g,
      (__attribute__((address_space(3))) unsigned int*)lds, 16, 0, 0);
}

// GEMM1 (LDS-free K-loop, PINNED distance-3 pipeline): 128x128 tile, BK=64,
// 4 waves (2m x 2n). Fragment-order operands; each fragment = 1 contiguous
// 1KB load. LD(0..2); loop { LD(ph+3); SB; MM(ph); SB; } with 4 named sets.
// LDS only for the C-stage epilogue (relu+bias -> Hp OLD packed order).
__global__ __launch_bounds__(256)
void k_gemm1(const int* __restrict__ hdr,
             const __hip_bfloat16* __restrict__ Ap,
             const __hip_bfloat16* __restrict__ Bp,
             const float* __restrict__ bias,
             __hip_bfloat16* __restrict__ Hout) {
  constexpr int NS = 8, NT = 16, NPH = 2 * NS;
  const int* tb = hdr + 13;
  const int total = tb[4];

  __shared__ __align__(16) char LDS[34816];   // C-stage only (128 x 272B)

  const int idx = blockIdx.x;
  if (idx >= total) return;
  const int qc = total >> 3, rc = total & 7;
  const int xcd = idx & 7;
  const int cbase = (xcd < rc) ? xcd * (qc + 1) : rc * (qc + 1) + (xcd - rc) * qc;
  const int w = cbase + (idx >> 3);

  const int tid = threadIdx.x, lane = tid & 63, wv = tid >> 6;
  const int wm = (wv >> 1) << 6, wn = (wv & 1) << 6;
  const int l15 = lane & 15, lq = lane >> 4;

  int g = 0;
  while (tb[g + 1] <= w) ++g;
  const int local = w - tb[g];
  const int mt = local / NT, nt = local % NT;
  const int cnt = hdr[g];
  int nrows = cnt - (mt << 7);
  nrows = nrows > 128 ? 128 : nrows;

  const int amt = (hdr[13 + g] >> 4) + mt;
  const __hip_bfloat16* aF = Ap + (((size_t)amt * NS) << 13) +
                             (((wv >> 1) << 2) << 9) + lane * 8;
  const __hip_bfloat16* bF = Bp + (((size_t)(g * NT + nt) * NS) << 13) +
                             (((wv & 1) << 2) << 9) + lane * 8;

  f32x4 acc[4][4];
  const f32x4 fz = {0.f, 0.f, 0.f, 0.f};
#pragma unroll
  for (int m = 0; m < 4; ++m)
#pragma unroll
    for (int n = 0; n < 4; ++n) acc[m][n] = fz;

  s16x8 a0[4], b0[4], a1[4], b1[4], a2[4], b2[4], a3[4], b3[4];
  auto LD = [&](int ph, s16x8* a, s16x8* b) {
    const size_t o = (size_t)ph << 12;
#pragma unroll
    for (int i = 0; i < 4; ++i) {
      a[i] = *(const s16x8*)(aF + o + (i << 9));
      b[i] = *(const s16x8*)(bF + o + (i << 9));
    }
  };
  auto MM = [&](s16x8* a, s16x8* b) {
    __builtin_amdgcn_s_setprio(1);
#pragma unroll
    for (int m = 0; m < 4; ++m)
#pragma unroll
      for (int n = 0; n < 4; ++n)
        acc[m][n] = mfma16(a[m], b[n], acc[m][n]);
    __builtin_amdgcn_s_setprio(0);
  };

  LD(0, a0, b0); SB();
  LD(1, a1, b1); SB();
  LD(2, a2, b2); SB();
#pragma unroll
  for (int ph = 0; ph < NPH; ph += 4) {
    if (ph + 3 < NPH) LD(ph + 3, a3, b3);
    SB(); MM(a0, b0); SB();
    if (ph + 4 < NPH) LD(ph + 4, a0, b0);
    SB(); MM(a1, b1); SB();
    if (ph + 5 < NPH) LD(ph + 5, a1, b1);
    SB(); MM(a2, b2); SB();
    if (ph + 6 < NPH) LD(ph + 6, a2, b2);
    SB(); MM(a3, b3); SB();
  }
  asm volatile("s_nop 7\ns_nop 7\ns_nop 7");    // MFMA->VALU hazard guard

  // epilogue: relu+bias via LDS C-stage (stride 272), then 128B stores into
  // Hp's OLD packed layout (GEMM2 LDS path consumes it).
  const int rq = lq << 2;
#pragma unroll
  for (int n = 0; n < 4; ++n) {
    const int col = wn + (n << 4) + l15;
    const float bv = bias[g * FDIM + (nt << 7) + col];
#pragma unroll
    for (int m = 0; m < 4; ++m)
#pragma unroll
      for (int j = 0; j < 4; ++j) {
        const int row = wm + (m << 4) + rq + j;
        float v = acc[m][n][j] + bv;
        v = v > 0.f ? v : 0.f;
        *(__hip_bfloat16*)(LDS + row * 272 + col * 2) = __float2bfloat16(v);
      }
  }
  __syncthreads();
  const int r = tid >> 1, hf = tid & 1;
  if (r < nrows) {
    const char* src = LDS + r * 272 + hf * 128;
    const size_t tIdx =
        ((size_t)((hdr[18 + g] >> 2) + mt) * 32 + (nt << 1) + hf);
    char* dst = (char*)(Hout + (tIdx << 13) + r * 64);
#pragma unroll
    for (int q = 0; q < 8; ++q)
      *(s16x8*)(dst + q * 16) = *(const s16x8*)(src + q * 16);
  }
}

// GEMM2: LDS + T4 depth-2 counted pipeline (128x128, BK=64), r19-verbatim.
// A = Hp packed old-order (K=2048), B = W2p; +bias; fp32 scatter via perm.
__global__ __launch_bounds__(256, 2)
void k_gemm2(const int* __restrict__ hdr, const int* __restrict__ perm,
             const __hip_bfloat16* __restrict__ Ap,
             const __hip_bfloat16* __restrict__ Bp,
             const float* __restrict__ bias, float* __restrict__ Yout) {
  constexpr int NS = 32;
  constexpr int NT = 4;
  constexpr int NF = HDIM;
  const int* tb = hdr + 18;
  const int total = tb[4];

  __shared__ __align__(16) char LDS[65536];
  char* As = LDS;
  char* Bs = LDS + 32768;

  const int idx = blockIdx.x;
  if (idx >= total) return;
  const int qc = total >> 3, rc = total & 7;
  const int xcd = idx & 7;
  const int cbase = (xcd < rc) ? xcd * (qc + 1) : rc * (qc + 1) + (xcd - rc) * qc;
  const int w = cbase + (idx >> 3);

  const int tid = threadIdx.x, lane = tid & 63, wv = tid >> 6;
  const int wm = (wv >> 1) << 6, wn = (wv & 1) << 6;
  const int l15 = lane & 15, lq = lane >> 4;
  const int rsub = lane >> 3, c8 = lane & 7;

  int g = 0;
  while (tb[g + 1] <= w) ++g;
  const int local = w - tb[g];
  const int mt = local / NT, nt = local % NT;
  const int cnt = hdr[g], off = hdr[8 + g];
  int nrows = cnt - (mt << 7);
  nrows = nrows > 128 ? 128 : nrows;

  const int amt = (hdr[18 + g] >> 2) + mt;
  const int lelem = ((wv << 5) + rsub) * 64 + ((c8 ^ rsub) << 3);
  const __hip_bfloat16* abase = Ap + (((size_t)amt * NS) << 13) + lelem;
  const __hip_bfloat16* bbase =
      Bp + (((size_t)(g * NT + nt) * NS) << 13) + lelem;

  f32x4 acc[4][4];
  const f32x4 fz = {0.f, 0.f, 0.f, 0.f};
#pragma unroll
  for (int m = 0; m < 4; ++m)
#pragma unroll
    for (int n = 0; n < 4; ++n) acc[m][n] = fz;

  auto STAGE = [&](int s, int p) {
    const size_t so = (size_t)s << 13;
    char* Ad = As + (p << 14) + (wv << 12);
    char* Bd = Bs + (p << 14) + (wv << 12);
#pragma unroll
    for (int i = 0; i < 4; ++i) {
      gload16(abase + so + (i << 9), Ad + (i << 10));
      gload16(bbase + so + (i << 9), Bd + (i << 10));
    }
  };
  auto COMPUTE = [&](int p) {
    const char* Ab = As + (p << 14);
    const char* Bb = Bs + (p << 14);
#pragma unroll
    for (int kk = 0; kk < 2; ++kk) {
      const int kb = (kk << 6) + (lq << 4);
      s16x8 a[4], b[4];
#pragma unroll
      for (int m = 0; m < 4; ++m) {
        const int row = wm + (m << 4) + l15;
        a[m] = *(const s16x8*)(Ab + (row << 7) + (kb ^ ((row & 7) << 4)));
      }
#pragma unroll
      for (int n = 0; n < 4; ++n) {
        const int row = wn + (n << 4) + l15;
        b[n] = *(const s16x8*)(Bb + (row << 7) + (kb ^ ((row & 7) << 4)));
      }
      __builtin_amdgcn_s_setprio(1);
#pragma unroll
      for (int m = 0; m < 4; ++m)
#pragma unroll
        for (int n = 0; n < 4; ++n)
          acc[m][n] = mfma16(a[m], b[n], acc[m][n]);
      __builtin_amdgcn_s_setprio(0);
    }
  };

  STAGE(0, 0);
  for (int s = 0; s < NS; ++s) {
    const int p = s & 1;
    if (s + 1 < NS) {
      STAGE(s + 1, p ^ 1);
      asm volatile("s_waitcnt vmcnt(8)" ::: "memory");
    } else {
      asm volatile("s_waitcnt vmcnt(0)" ::: "memory");
    }
    __builtin_amdgcn_s_barrier();
    asm volatile("" ::: "memory");
    COMPUTE(p);
    asm volatile("" ::: "memory");
    __builtin_amdgcn_s_barrier();
    asm volatile("" ::: "memory");
  }
  asm volatile("s_nop 7\ns_nop 7\ns_nop 7");

  const int rq = lq << 2;
#pragma unroll
  for (int n = 0; n < 4; ++n) {
    const int ncol = (nt << 7) + wn + (n << 4) + l15;
    const float bv = bias[g * NF + ncol];
#pragma unroll
    for (int m = 0; m < 4; ++m)
#pragma unroll
      for (int j = 0; j < 4; ++j) {
        const int rl = wm + (m << 4) + rq + j;
        if (rl < nrows) {
          const int tok = perm[off + (mt << 7) + rl];
          Yout[((size_t)tok << 9) + ncol] = acc[m][n][j] + bv;
        }
      }
  }
}

extern "C" void kernel_launch(void* const* d_in, const int* in_sizes, int n_in,
                              void* d_out, int out_size, void* d_ws,
                              size_t ws_size, hipStream_t stream) {
  const float* x    = (const float*)d_in[0];
  const int* b_seq  = (const int*)d_in[1];
  const float* W1   = (const float*)d_in[2];
  const float* B1   = (const float*)d_in[3];
  const float* W2   = (const float*)d_in[4];
  const float* B2   = (const float*)d_in[5];
  float* out        = (float*)d_out;

  char* ws = (char*)d_ws;
  int* hdr  = (int*)ws;                          // 1 KB header
  int* perm = (int*)(ws + 1024);                 // 64 KB
  __hip_bfloat16* xa  = (__hip_bfloat16*)(ws + 66560);   // frag order
  __hip_bfloat16* W1p = xa + (size_t)MAXMT * 8 * 8192;   // frag order
  __hip_bfloat16* W2p = W1p + (size_t)NEXP * FDIM * HDIM;// old packed order
  __hip_bfloat16* Hp  = W2p + (size_t)NEXP * HDIM * FDIM;// old packed order

  const int n4 = NTOK * HDIM / 4;

  k_init<<<1024, 256, 0, stream>>>((const int4*)b_seq, b_seq, (float4*)out,
                                   n4, hdr);
  k_fill<<<NTOK / 256, 256, 0, stream>>>(b_seq, hdr, perm);
  k_pack_a<<<MAXMT * 8, 256, 0, stream>>>(x, hdr, perm, xa);
  k_transpose_both<<<2048, 256, 0, stream>>>(W1, W1p, W2, W2p);
  // grids cover worst-case tile counts; blocks past the actual total exit
  k_gemm1<<<2112, 256, 0, stream>>>(hdr, xa, W1p, B1, Hp);
  k_gemm2<<<528, 256, 0, stream>>>(hdr, perm, Hp, W2p, B2, out);
}

// Round 21
// 124.986 us; speedup vs baseline: 1.0386x; 1.0254x over previous
//
#include <hip/hip_runtime.h>
#include <hip/hip_bf16.h>

// ---------------------------------------------------------------------------
// BehaviorSpecificPFF: token-routed 4-expert FFN.
//   y[tok] = relu(x[tok] @ W1[g] + B1[g]) @ W2[g] + B2[g],  g = b_seq[tok]-1
//   b_seq==0 -> zeros.
// Round 21: HYBRID GEMM2 -- A-operand frag-direct to registers (fast path,
// r18-proven addressing; Hp written in FRAGMENT order by GEMM1's r18-proven
// epilogue), B-operand via LDS + counted-vmcnt staging (r20-proven B-half).
// Per K-step batch = 4 B-gloads + 8 A-loads between vmcnt fences ->
// vmcnt(12) retires exactly the prior step's batch. LDS 64->32KB.
// GEMM1 = r18 kernel (pinned distance-3 frag-direct + frag-Hp epilogue).
// Prep identical to r20.
// ---------------------------------------------------------------------------

typedef short s16x8 __attribute__((ext_vector_type(8)));
typedef float f32x4 __attribute__((ext_vector_type(4)));

#define NTOK   16384
#define HDIM   512
#define FDIM   2048
#define NEXP   4
#define MAXMT  132   // worst-case total 128-row m-tiles (4 experts)
#define SB()   __builtin_amdgcn_sched_barrier(0)

// ---- header layout (ints) in ws ----
// [0..3] counts  [4..7] cursors  [8..12] token offsets ([12]=total)
// [13..17] gemm1 tile bases, mt-base = hdr[13+g]>>4 ([17]=total)
// [18..22] gemm2 tile bases, mt-base = hdr[18+g]>>2

__global__ void k_init(const int4* __restrict__ b4,
                       const int* __restrict__ b_seq,
                       float4* __restrict__ out, int n4,
                       int* __restrict__ hdr) {
  if (blockIdx.x == 0) {   // fused count+scan
    __shared__ int cnt[4];
    const int t = threadIdx.x;
    if (t < 4) cnt[t] = 0;
    __syncthreads();
    int c0 = 0, c1 = 0, c2 = 0, c3 = 0;
    for (int i = t; i < NTOK / 4; i += 256) {
      int4 v = b4[i];
      c0 += (v.x == 1) + (v.y == 1) + (v.z == 1) + (v.w == 1);
      c1 += (v.x == 2) + (v.y == 2) + (v.z == 2) + (v.w == 2);
      c2 += (v.x == 3) + (v.y == 3) + (v.z == 3) + (v.w == 3);
      c3 += (v.x == 4) + (v.y == 4) + (v.z == 4) + (v.w == 4);
    }
    if (c0) atomicAdd(&cnt[0], c0);
    if (c1) atomicAdd(&cnt[1], c1);
    if (c2) atomicAdd(&cnt[2], c2);
    if (c3) atomicAdd(&cnt[3], c3);
    __syncthreads();
    if (t == 0) {
      int off = 0, b1 = 0, b2 = 0;
      for (int g = 0; g < 4; ++g) {
        int c = cnt[g];
        hdr[g] = c;
        hdr[8 + g] = off;
        hdr[4 + g] = off;   // cursor
        hdr[13 + g] = b1;
        hdr[18 + g] = b2;
        int mt = (c + 127) >> 7;
        off += c;
        b1 += mt * 16;
        b2 += mt * 4;
      }
      hdr[12] = off; hdr[17] = b1; hdr[22] = b2;
    }
  }
  float4 z; z.x = z.y = z.z = z.w = 0.f;
  for (int i = blockIdx.x * blockDim.x + threadIdx.x; i < n4;
       i += gridDim.x * blockDim.x) {
    // non-pad out rows are fully rewritten by GEMM2 every call; only padding
    // rows need zeros (out float4-row token = i>>7).
    if (b_seq[i >> 7] == 0) out[i] = z;
  }
}

// LDS-aggregated fill: one global atomic per (block, expert).
__global__ void k_fill(const int* __restrict__ b_seq, int* __restrict__ hdr,
                       int* __restrict__ perm) {
  __shared__ int lcnt[4], base[4];
  const int tid = threadIdx.x;
  if (tid < 4) lcnt[tid] = 0;
  __syncthreads();
  const int i = blockIdx.x * 256 + tid;
  const int g = b_seq[i];
  int r = -1;
  if (g > 0) r = atomicAdd(&lcnt[g - 1], 1);
  __syncthreads();
  if (tid < 4) {
    int c = lcnt[tid];
    base[tid] = c ? atomicAdd(&hdr[4 + tid], c) : 0;
  }
  __syncthreads();
  if (g > 0) perm[base[g - 1] + r] = i;
}

// Gather + convert x into FRAGMENT-ORDER A tiles:
//   xa[mtile][ks][kk][rb][lane]: lane l holds row rb*16+(l&15),
//   k = ks*64 + kk*32 + (l>>4)*8 .. +7 (16B per lane-slot).
// One block per (mtile, ks). OOB rows zero-filled.
__global__ __launch_bounds__(256)
void k_pack_a(const float* __restrict__ x, const int* __restrict__ hdr,
              const int* __restrict__ perm, __hip_bfloat16* __restrict__ xa) {
  const int nmt = hdr[17] >> 4;
  const int b = blockIdx.x >> 3, ks = blockIdx.x & 7;
  if (b >= nmt) return;
  int g = 0;
  while ((hdr[13 + g + 1] >> 4) <= b) ++g;
  const int mt = b - (hdr[13 + g] >> 4);
  const int off = hdr[8 + g], cnt = hdr[g];
  int nrows = cnt - (mt << 7);
  nrows = nrows > 128 ? 128 : nrows;
  const int t = threadIdx.x;
  const int kk = t >> 7, rb = (t >> 4) & 7, l0 = (t & 15) << 2;
  __hip_bfloat16* dst = xa + ((size_t)b << 16) + (ks << 13) +
                        ((((kk << 3) + rb) << 6) + l0) * 8;
#pragma unroll
  for (int i = 0; i < 4; ++i) {
    const int l = l0 + i;
    const int row = (rb << 4) + (l & 15);
    union { __hip_bfloat16 b16[8]; s16x8 v; } u;
    if (row < nrows) {
      const float* src = x + (size_t)perm[off + (mt << 7) + row] * HDIM +
                         (ks << 6) + (kk << 5) + ((l >> 4) << 3);
      float4 v0 = *(const float4*)(src);
      float4 v1 = *(const float4*)(src + 4);
      u.b16[0] = __float2bfloat16(v0.x); u.b16[1] = __float2bfloat16(v0.y);
      u.b16[2] = __float2bfloat16(v0.z); u.b16[3] = __float2bfloat16(v0.w);
      u.b16[4] = __float2bfloat16(v1.x); u.b16[5] = __float2bfloat16(v1.y);
      u.b16[6] = __float2bfloat16(v1.z); u.b16[7] = __float2bfloat16(v1.w);
    } else {
      const s16x8 zz = {0, 0, 0, 0, 0, 0, 0, 0};
      u.v = zz;
    }
    *(s16x8*)(dst + i * 8) = u.v;
  }
}

// Fused W1+W2 transpose/convert (one launch, 2048 blocks).
// Blocks [0,1024): W1 (R=HDIM, C=FDIM) -> W1p in FRAGMENT order.
// Blocks [1024,2048): W2 (R=FDIM, C=HDIM) -> W2p in OLD packed order.
__global__ __launch_bounds__(256)
void k_transpose_both(const float* __restrict__ W1,
                      __hip_bfloat16* __restrict__ W1p,
                      const float* __restrict__ W2,
                      __hip_bfloat16* __restrict__ W2p) {
  __shared__ float tile[64][69];   // pad 69: conflict-free col reads
  const bool first = blockIdx.x < 1024;
  const int id = first ? blockIdx.x : blockIdx.x - 1024;
  const int R = first ? HDIM : FDIM;
  const int C = first ? FDIM : HDIM;
  const int nbx = C >> 6, nby = R >> 6;
  const int bx = id % nbx, rest = id / nbx;
  const int by = rest % nby, g = rest / nby;
  const float* S = (first ? W1 : W2) + (size_t)g * R * C;
  __hip_bfloat16* dst = first ? W1p : W2p;
  const int c0 = bx << 6, r0 = by << 6;
  const int t = threadIdx.x;
  const int lr = t >> 4, lc = (t & 15) << 2;
#pragma unroll
  for (int p = 0; p < 4; ++p) {
    float4 v = *(const float4*)(S + (size_t)(r0 + lr + p * 16) * C + c0 + lc);
    float* tr = &tile[lr + p * 16][lc];
    tr[0] = v.x; tr[1] = v.y; tr[2] = v.z; tr[3] = v.w;
  }
  __syncthreads();
  const int c = t >> 2, rq = t & 3;
  union { __hip_bfloat16 b[8]; s16x8 v; } u0, u1;
#pragma unroll
  for (int j = 0; j < 8; ++j) {
    u0.b[j] = __float2bfloat16(tile[rq * 16 + j][c]);
    u1.b[j] = __float2bfloat16(tile[rq * 16 + 8 + j][c]);
  }
  const int rI = c0 + c, kI = r0 + rq * 16;
  const int tl = g * (C >> 7) + (rI >> 7);
  if (!first) {
    // old packed order [tile][ks][row128][k64]
    const size_t idx = (((size_t)tl * (R >> 6) + (kI >> 6)) << 13) +
                       ((rI & 127) << 6) + (kI & 63);
    *(s16x8*)(dst + idx) = u0.v;
    *(s16x8*)(dst + idx + 8) = u1.v;
  } else {
    // fragment order [tile][ks][kk][rb][lane]
    const int ks = kI >> 6, kk = (kI >> 5) & 1, lq0 = (kI >> 3) & 3;
    const int rb = (rI & 127) >> 4;
    const size_t base = (((size_t)tl * (R >> 6) + ks) << 13) +
                        ((((kk << 3) + rb) << 6) + (lq0 << 4) + (rI & 15)) * 8;
    *(s16x8*)(dst + base) = u0.v;          // lane lq0*16 + l15
    *(s16x8*)(dst + base + 128) = u1.v;    // lane (lq0+1)*16 + l15
  }
}

__device__ __forceinline__ f32x4 mfma16(s16x8 a, s16x8 b, f32x4 c) {
  asm("v_mfma_f32_16x16x32_bf16 %0, %1, %2, %0" : "+v"(c) : "v"(a), "v"(b));
  return c;
}

__device__ __forceinline__ void gload16(const void* g, void* lds) {
  __builtin_amdgcn_global_load_lds(
      (const __attribute__((address_space(1))) unsigned int*)g,
      (__attribute__((address_space(3))) unsigned int*)lds, 16, 0, 0);
}

// GEMM1 (r18-proven): LDS-free K-loop, pinned distance-3 pipeline, 128x128
// tile, BK=64, 4 waves (2m x 2n). Fragment-order operands; each fragment =
// 1 contiguous 1KB load. Epilogue: relu+bias via LDS C-stage, 16B stores
// into Hp in FRAGMENT order (GEMM2 A-side consumes directly).
__global__ __launch_bounds__(256)
void k_gemm1(const int* __restrict__ hdr,
             const __hip_bfloat16* __restrict__ Ap,
             const __hip_bfloat16* __restrict__ Bp,
             const float* __restrict__ bias,
             __hip_bfloat16* __restrict__ Hout) {
  constexpr int NS = 8, NT = 16, NPH = 2 * NS;
  const int* tb = hdr + 13;
  const int total = tb[4];

  __shared__ __align__(16) char LDS[34816];   // C-stage only (128 x 272B)

  const int idx = blockIdx.x;
  if (idx >= total) return;
  const int qc = total >> 3, rc = total & 7;
  const int xcd = idx & 7;
  const int cbase = (xcd < rc) ? xcd * (qc + 1) : rc * (qc + 1) + (xcd - rc) * qc;
  const int w = cbase + (idx >> 3);

  const int tid = threadIdx.x, lane = tid & 63, wv = tid >> 6;
  const int wm = (wv >> 1) << 6, wn = (wv & 1) << 6;
  const int l15 = lane & 15, lq = lane >> 4;

  int g = 0;
  while (tb[g + 1] <= w) ++g;
  const int local = w - tb[g];
  const int mt = local / NT, nt = local % NT;
  const int cnt = hdr[g];
  int nrows = cnt - (mt << 7);
  nrows = nrows > 128 ? 128 : nrows;

  const int amt = (hdr[13 + g] >> 4) + mt;
  const __hip_bfloat16* aF = Ap + (((size_t)amt * NS) << 13) +
                             (((wv >> 1) << 2) << 9) + lane * 8;
  const __hip_bfloat16* bF = Bp + (((size_t)(g * NT + nt) * NS) << 13) +
                             (((wv & 1) << 2) << 9) + lane * 8;

  f32x4 acc[4][4];
  const f32x4 fz = {0.f, 0.f, 0.f, 0.f};
#pragma unroll
  for (int m = 0; m < 4; ++m)
#pragma unroll
    for (int n = 0; n < 4; ++n) acc[m][n] = fz;

  s16x8 a0[4], b0[4], a1[4], b1[4], a2[4], b2[4], a3[4], b3[4];
  auto LD = [&](int ph, s16x8* a, s16x8* b) {
    const size_t o = (size_t)ph << 12;
#pragma unroll
    for (int i = 0; i < 4; ++i) {
      a[i] = *(const s16x8*)(aF + o + (i << 9));
      b[i] = *(const s16x8*)(bF + o + (i << 9));
    }
  };
  auto MM = [&](s16x8* a, s16x8* b) {
    __builtin_amdgcn_s_setprio(1);
#pragma unroll
    for (int m = 0; m < 4; ++m)
#pragma unroll
      for (int n = 0; n < 4; ++n)
        acc[m][n] = mfma16(a[m], b[n], acc[m][n]);
    __builtin_amdgcn_s_setprio(0);
  };

  LD(0, a0, b0); SB();
  LD(1, a1, b1); SB();
  LD(2, a2, b2); SB();
#pragma unroll
  for (int ph = 0; ph < NPH; ph += 4) {
    if (ph + 3 < NPH) LD(ph + 3, a3, b3);
    SB(); MM(a0, b0); SB();
    if (ph + 4 < NPH) LD(ph + 4, a0, b0);
    SB(); MM(a1, b1); SB();
    if (ph + 5 < NPH) LD(ph + 5, a1, b1);
    SB(); MM(a2, b2); SB();
    if (ph + 6 < NPH) LD(ph + 6, a2, b2);
    SB(); MM(a3, b3); SB();
  }
  asm volatile("s_nop 7\ns_nop 7\ns_nop 7");    // MFMA->VALU hazard guard

  // epilogue (r18-proven): relu+bias via LDS C-stage (stride 272), then 16B
  // stores into Hp in FRAGMENT order.
  const int rq = lq << 2;
#pragma unroll
  for (int n = 0; n < 4; ++n) {
    const int col = wn + (n << 4) + l15;
    const float bv = bias[g * FDIM + (nt << 7) + col];
#pragma unroll
    for (int m = 0; m < 4; ++m)
#pragma unroll
      for (int j = 0; j < 4; ++j) {
        const int row = wm + (m << 4) + rq + j;
        float v = acc[m][n][j] + bv;
        v = v > 0.f ? v : 0.f;
        *(__hip_bfloat16*)(LDS + row * 272 + col * 2) = __float2bfloat16(v);
      }
  }
  __syncthreads();
  const int r = tid >> 1, hf = tid & 1;
  if (r < nrows) {
    const char* src = LDS + r * 272 + hf * 128;   // 64 bf16 for kstep 2nt+hf
    const int hmt = (hdr[18 + g] >> 2) + mt;
    __hip_bfloat16* dblk =
        Hout + (((size_t)hmt * 32 + (nt << 1) + hf) << 13);
    const int rb = r >> 4, l15r = r & 15;
#pragma unroll
    for (int kk2 = 0; kk2 < 2; ++kk2)
#pragma unroll
      for (int lq2 = 0; lq2 < 4; ++lq2) {
        s16x8 v = *(const s16x8*)(src + kk2 * 64 + lq2 * 16);
        *(s16x8*)(dblk +
                  ((((kk2 << 3) + rb) << 6) + (lq2 << 4) + l15r) * 8) = v;
      }
  }
}

// GEMM2 HYBRID: 128x128 tile, BK=64, 4 waves (2m x 2n).
// A (Hp, fragment order) -> registers, 2 named sets (r18-proven addressing).
// B (W2p, old packed order) -> LDS double-buffer via gload16 (r20-proven).
// Per K-step batch between vmcnt fences = 4 B-gloads + 8 A-loads ->
// vmcnt(12) retires exactly the prior step's batch; next stays in flight.
// fp32 scatter epilogue via perm.
__global__ __launch_bounds__(256)
void k_gemm2(const int* __restrict__ hdr, const int* __restrict__ perm,
             const __hip_bfloat16* __restrict__ Ap,
             const __hip_bfloat16* __restrict__ Bp,
             const float* __restrict__ bias, float* __restrict__ Yout) {
  constexpr int NS = 32, NT = 4;
  const int* tb = hdr + 18;
  const int total = tb[4];

  __shared__ __align__(16) char LDS[32768];   // B dbuf: 2 x 16KB

  const int idx = blockIdx.x;
  if (idx >= total) return;
  const int qc = total >> 3, rc = total & 7;
  const int xcd = idx & 7;
  const int cbase = (xcd < rc) ? xcd * (qc + 1) : rc * (qc + 1) + (xcd - rc) * qc;
  const int w = cbase + (idx >> 3);

  const int tid = threadIdx.x, lane = tid & 63, wv = tid >> 6;
  const int wm = (wv >> 1) << 6, wn = (wv & 1) << 6;
  const int l15 = lane & 15, lq = lane >> 4;
  const int rsub = lane >> 3, c8 = lane & 7;

  int g = 0;
  while (tb[g + 1] <= w) ++g;
  const int local = w - tb[g];
  const int mt = local / NT, nt = local % NT;
  const int cnt = hdr[g], off = hdr[8 + g];
  int nrows = cnt - (mt << 7);
  nrows = nrows > 128 ? 128 : nrows;

  const int amt = (hdr[18 + g] >> 2) + mt;
  // A frag-direct base (r18): wave row-half selects 4 frag-blocks
  const __hip_bfloat16* aF = Ap + (((size_t)amt * NS) << 13) +
                             (((wv >> 1) << 2) << 9) + lane * 8;
  // B LDS-staged source (r20): per-thread 1KB-contiguous units, XOR-in-block
  const int lelem = ((wv << 5) + rsub) * 64 + ((c8 ^ rsub) << 3);
  const __hip_bfloat16* bbase =
      Bp + (((size_t)(g * NT + nt) * NS) << 13) + lelem;

  f32x4 acc[4][4];
  const f32x4 fz = {0.f, 0.f, 0.f, 0.f};
#pragma unroll
  for (int m = 0; m < 4; ++m)
#pragma unroll
    for (int n = 0; n < 4; ++n) acc[m][n] = fz;

  s16x8 aP[8], aQ[8];   // two named A sets (static indexing)
  auto LDA = [&](int s, s16x8* a) {
    const size_t o = (size_t)s << 13;   // phases 2s (=o) and 2s+1 (=o+4096)
#pragma unroll
    for (int i = 0; i < 4; ++i) {
      a[i] = *(const s16x8*)(aF + o + (i << 9));
      a[4 + i] = *(const s16x8*)(aF + o + 4096 + (i << 9));
    }
  };
  auto STAGEB = [&](int s, int p) {
    const size_t so = (size_t)s << 13;
    char* Bd = LDS + (p << 14) + (wv << 12);
#pragma unroll
    for (int i = 0; i < 4; ++i)
      gload16(bbase + so + (i << 9), Bd + (i << 10));
  };
  auto COMP = [&](int p, s16x8* a) {
    const char* Bb = LDS + (p << 14);
#pragma unroll
    for (int kk = 0; kk < 2; ++kk) {
      const int kb = (kk << 6) + (lq << 4);
      s16x8 b[4];
#pragma unroll
      for (int n = 0; n < 4; ++n) {
        const int row = wn + (n << 4) + l15;
        b[n] = *(const s16x8*)(Bb + (row << 7) + (kb ^ ((row & 7) << 4)));
      }
      __builtin_amdgcn_s_setprio(1);
#pragma unroll
      for (int m = 0; m < 4; ++m)
#pragma unroll
        for (int n = 0; n < 4; ++n)
          acc[m][n] = mfma16(a[(kk << 2) + m], b[n], acc[m][n]);
      __builtin_amdgcn_s_setprio(0);
    }
  };

  // prologue: batch(0) = B(0) + A(0)->aP
  STAGEB(0, 0);
  LDA(0, aP);
  asm volatile("s_waitcnt vmcnt(0)" ::: "memory");
  __builtin_amdgcn_s_barrier();
  asm volatile("" ::: "memory");
  for (int s = 0; s < NS; s += 2) {
    // step s: compute (buf0, aP); prefetch batch(s+1) -> (buf1, aQ)
    if (s + 1 < NS) {
      STAGEB(s + 1, 1);
      LDA(s + 1, aQ);
      asm volatile("s_waitcnt vmcnt(12)" ::: "memory");  // batch(s) landed
    } else {
      asm volatile("s_waitcnt vmcnt(0)" ::: "memory");
    }
    __builtin_amdgcn_s_barrier();
    asm volatile("" ::: "memory");
    COMP(0, aP);
    asm volatile("" ::: "memory");
    __builtin_amdgcn_s_barrier();   // buf0 reads done before next overwrite
    asm volatile("" ::: "memory");
    // step s+1: compute (buf1, aQ); prefetch batch(s+2) -> (buf0, aP)
    if (s + 2 < NS) {
      STAGEB(s + 2, 0);
      LDA(s + 2, aP);
      asm volatile("s_waitcnt vmcnt(12)" ::: "memory");  // batch(s+1) landed
    } else {
      asm volatile("s_waitcnt vmcnt(0)" ::: "memory");
    }
    __builtin_amdgcn_s_barrier();
    asm volatile("" ::: "memory");
    COMP(1, aQ);
    asm volatile("" ::: "memory");
    __builtin_amdgcn_s_barrier();   // buf1 reads done before next overwrite
    asm volatile("" ::: "memory");
  }
  asm volatile("s_nop 7\ns_nop 7\ns_nop 7");   // MFMA->VALU hazard guard

  const int rq = lq << 2;
#pragma unroll
  for (int n = 0; n < 4; ++n) {
    const int ncol = (nt << 7) + wn + (n << 4) + l15;
    const float bv = bias[g * HDIM + ncol];
#pragma unroll
    for (int m = 0; m < 4; ++m)
#pragma unroll
      for (int j = 0; j < 4; ++j) {
        const int rl = wm + (m << 4) + rq + j;
        if (rl < nrows) {
          const int tok = perm[off + (mt << 7) + rl];
          Yout[((size_t)tok << 9) + ncol] = acc[m][n][j] + bv;
        }
      }
  }
}

extern "C" void kernel_launch(void* const* d_in, const int* in_sizes, int n_in,
                              void* d_out, int out_size, void* d_ws,
                              size_t ws_size, hipStream_t stream) {
  const float* x    = (const float*)d_in[0];
  const int* b_seq  = (const int*)d_in[1];
  const float* W1   = (const float*)d_in[2];
  const float* B1   = (const float*)d_in[3];
  const float* W2   = (const float*)d_in[4];
  const float* B2   = (const float*)d_in[5];
  float* out        = (float*)d_out;

  char* ws = (char*)d_ws;
  int* hdr  = (int*)ws;                          // 1 KB header
  int* perm = (int*)(ws + 1024);                 // 64 KB
  __hip_bfloat16* xa  = (__hip_bfloat16*)(ws + 66560);   // frag order
  __hip_bfloat16* W1p = xa + (size_t)MAXMT * 8 * 8192;   // frag order
  __hip_bfloat16* W2p = W1p + (size_t)NEXP * FDIM * HDIM;// old packed order
  __hip_bfloat16* Hp  = W2p + (size_t)NEXP * HDIM * FDIM;// FRAGMENT order

  const int n4 = NTOK * HDIM / 4;

  k_init<<<1024, 256, 0, stream>>>((const int4*)b_seq, b_seq, (float4*)out,
                                   n4, hdr);
  k_fill<<<NTOK / 256, 256, 0, stream>>>(b_seq, hdr, perm);
  k_pack_a<<<MAXMT * 8, 256, 0, stream>>>(x, hdr, perm, xa);
  k_transpose_both<<<2048, 256, 0, stream>>>(W1, W1p, W2, W2p);
  // grids cover worst-case tile counts; blocks past the actual total exit
  k_gemm1<<<2112, 256, 0, stream>>>(hdr, xa, W1p, B1, Hp);
  k_gemm2<<<528, 256, 0, stream>>>(hdr, perm, Hp, W2p, B2, out);
}

// Round 22
// 119.034 us; speedup vs baseline: 1.0905x; 1.0500x over previous
//
#include <hip/hip_runtime.h>
#include <hip/hip_bf16.h>

// ---------------------------------------------------------------------------
// BehaviorSpecificPFF: token-routed 4-expert FFN.
//   y[tok] = relu(x[tok] @ W1[g] + B1[g]) @ W2[g] + B2[g],  g = b_seq[tok]-1
//   b_seq==0 -> zeros.
// Round 22: GEMM1 = r21 (pinned distance-3 frag-direct + FRAGMENT-order Hp
// epilogue; the frag-Hp writer is worth ~10us in GEMM1+prep, r18/r21 vs
// r19/r20). GEMM2 = r20's proven LDS+T4 counted depth-2 schedule on
// FRAGMENT-order operands: staging is linear (every wave-instr = 1KB
// contiguous), LDS fragment reads are uniform+lane*16 (no XOR swizzle).
// Hybrid GEMM2 (r21, 59.5us) falsified -> dropped. W2p now frag order.
// ---------------------------------------------------------------------------

typedef short s16x8 __attribute__((ext_vector_type(8)));
typedef float f32x4 __attribute__((ext_vector_type(4)));

#define NTOK   16384
#define HDIM   512
#define FDIM   2048
#define NEXP   4
#define MAXMT  132   // worst-case total 128-row m-tiles (4 experts)
#define SB()   __builtin_amdgcn_sched_barrier(0)

// ---- header layout (ints) in ws ----
// [0..3] counts  [4..7] cursors  [8..12] token offsets ([12]=total)
// [13..17] gemm1 tile bases, mt-base = hdr[13+g]>>4 ([17]=total)
// [18..22] gemm2 tile bases, mt-base = hdr[18+g]>>2

__global__ void k_init(const int4* __restrict__ b4,
                       const int* __restrict__ b_seq,
                       float4* __restrict__ out, int n4,
                       int* __restrict__ hdr) {
  if (blockIdx.x == 0) {   // fused count+scan
    __shared__ int cnt[4];
    const int t = threadIdx.x;
    if (t < 4) cnt[t] = 0;
    __syncthreads();
    int c0 = 0, c1 = 0, c2 = 0, c3 = 0;
    for (int i = t; i < NTOK / 4; i += 256) {
      int4 v = b4[i];
      c0 += (v.x == 1) + (v.y == 1) + (v.z == 1) + (v.w == 1);
      c1 += (v.x == 2) + (v.y == 2) + (v.z == 2) + (v.w == 2);
      c2 += (v.x == 3) + (v.y == 3) + (v.z == 3) + (v.w == 3);
      c3 += (v.x == 4) + (v.y == 4) + (v.z == 4) + (v.w == 4);
    }
    if (c0) atomicAdd(&cnt[0], c0);
    if (c1) atomicAdd(&cnt[1], c1);
    if (c2) atomicAdd(&cnt[2], c2);
    if (c3) atomicAdd(&cnt[3], c3);
    __syncthreads();
    if (t == 0) {
      int off = 0, b1 = 0, b2 = 0;
      for (int g = 0; g < 4; ++g) {
        int c = cnt[g];
        hdr[g] = c;
        hdr[8 + g] = off;
        hdr[4 + g] = off;   // cursor
        hdr[13 + g] = b1;
        hdr[18 + g] = b2;
        int mt = (c + 127) >> 7;
        off += c;
        b1 += mt * 16;
        b2 += mt * 4;
      }
      hdr[12] = off; hdr[17] = b1; hdr[22] = b2;
    }
  }
  float4 z; z.x = z.y = z.z = z.w = 0.f;
  for (int i = blockIdx.x * blockDim.x + threadIdx.x; i < n4;
       i += gridDim.x * blockDim.x) {
    // non-pad out rows are fully rewritten by GEMM2 every call; only padding
    // rows need zeros (out float4-row token = i>>7).
    if (b_seq[i >> 7] == 0) out[i] = z;
  }
}

// LDS-aggregated fill: one global atomic per (block, expert).
__global__ void k_fill(const int* __restrict__ b_seq, int* __restrict__ hdr,
                       int* __restrict__ perm) {
  __shared__ int lcnt[4], base[4];
  const int tid = threadIdx.x;
  if (tid < 4) lcnt[tid] = 0;
  __syncthreads();
  const int i = blockIdx.x * 256 + tid;
  const int g = b_seq[i];
  int r = -1;
  if (g > 0) r = atomicAdd(&lcnt[g - 1], 1);
  __syncthreads();
  if (tid < 4) {
    int c = lcnt[tid];
    base[tid] = c ? atomicAdd(&hdr[4 + tid], c) : 0;
  }
  __syncthreads();
  if (g > 0) perm[base[g - 1] + r] = i;
}

// Gather + convert x into FRAGMENT-ORDER A tiles:
//   xa[mtile][ks][kk][rb][lane]: lane l holds row rb*16+(l&15),
//   k = ks*64 + kk*32 + (l>>4)*8 .. +7 (16B per lane-slot).
// One block per (mtile, ks). OOB rows zero-filled.
__global__ __launch_bounds__(256)
void k_pack_a(const float* __restrict__ x, const int* __restrict__ hdr,
              const int* __restrict__ perm, __hip_bfloat16* __restrict__ xa) {
  const int nmt = hdr[17] >> 4;
  const int b = blockIdx.x >> 3, ks = blockIdx.x & 7;
  if (b >= nmt) return;
  int g = 0;
  while ((hdr[13 + g + 1] >> 4) <= b) ++g;
  const int mt = b - (hdr[13 + g] >> 4);
  const int off = hdr[8 + g], cnt = hdr[g];
  int nrows = cnt - (mt << 7);
  nrows = nrows > 128 ? 128 : nrows;
  const int t = threadIdx.x;
  const int kk = t >> 7, rb = (t >> 4) & 7, l0 = (t & 15) << 2;
  __hip_bfloat16* dst = xa + ((size_t)b << 16) + (ks << 13) +
                        ((((kk << 3) + rb) << 6) + l0) * 8;
#pragma unroll
  for (int i = 0; i < 4; ++i) {
    const int l = l0 + i;
    const int row = (rb << 4) + (l & 15);
    union { __hip_bfloat16 b16[8]; s16x8 v; } u;
    if (row < nrows) {
      const float* src = x + (size_t)perm[off + (mt << 7) + row] * HDIM +
                         (ks << 6) + (kk << 5) + ((l >> 4) << 3);
      float4 v0 = *(const float4*)(src);
      float4 v1 = *(const float4*)(src + 4);
      u.b16[0] = __float2bfloat16(v0.x); u.b16[1] = __float2bfloat16(v0.y);
      u.b16[2] = __float2bfloat16(v0.z); u.b16[3] = __float2bfloat16(v0.w);
      u.b16[4] = __float2bfloat16(v1.x); u.b16[5] = __float2bfloat16(v1.y);
      u.b16[6] = __float2bfloat16(v1.z); u.b16[7] = __float2bfloat16(v1.w);
    } else {
      const s16x8 zz = {0, 0, 0, 0, 0, 0, 0, 0};
      u.v = zz;
    }
    *(s16x8*)(dst + i * 8) = u.v;
  }
}

// Fused W1+W2 transpose/convert (one launch, 2048 blocks), BOTH to
// FRAGMENT order [tile][ks][kk][rb][lane].
// Blocks [0,1024): W1 (R=HDIM, C=FDIM); [1024,2048): W2 (R=FDIM, C=HDIM).
__global__ __launch_bounds__(256)
void k_transpose_both(const float* __restrict__ W1,
                      __hip_bfloat16* __restrict__ W1p,
                      const float* __restrict__ W2,
                      __hip_bfloat16* __restrict__ W2p) {
  __shared__ float tile[64][69];   // pad 69: conflict-free col reads
  const bool first = blockIdx.x < 1024;
  const int id = first ? blockIdx.x : blockIdx.x - 1024;
  const int R = first ? HDIM : FDIM;
  const int C = first ? FDIM : HDIM;
  const int nbx = C >> 6, nby = R >> 6;
  const int bx = id % nbx, rest = id / nbx;
  const int by = rest % nby, g = rest / nby;
  const float* S = (first ? W1 : W2) + (size_t)g * R * C;
  __hip_bfloat16* dst = first ? W1p : W2p;
  const int c0 = bx << 6, r0 = by << 6;
  const int t = threadIdx.x;
  const int lr = t >> 4, lc = (t & 15) << 2;
#pragma unroll
  for (int p = 0; p < 4; ++p) {
    float4 v = *(const float4*)(S + (size_t)(r0 + lr + p * 16) * C + c0 + lc);
    float* tr = &tile[lr + p * 16][lc];
    tr[0] = v.x; tr[1] = v.y; tr[2] = v.z; tr[3] = v.w;
  }
  __syncthreads();
  const int c = t >> 2, rq = t & 3;
  union { __hip_bfloat16 b[8]; s16x8 v; } u0, u1;
#pragma unroll
  for (int j = 0; j < 8; ++j) {
    u0.b[j] = __float2bfloat16(tile[rq * 16 + j][c]);
    u1.b[j] = __float2bfloat16(tile[rq * 16 + 8 + j][c]);
  }
  const int rI = c0 + c, kI = r0 + rq * 16;
  const int tl = g * (C >> 7) + (rI >> 7);
  const int ks = kI >> 6, kk = (kI >> 5) & 1, lq0 = (kI >> 3) & 3;
  const int rb = (rI & 127) >> 4;
  const size_t base = (((size_t)tl * (R >> 6) + ks) << 13) +
                      ((((kk << 3) + rb) << 6) + (lq0 << 4) + (rI & 15)) * 8;
  *(s16x8*)(dst + base) = u0.v;          // lane lq0*16 + l15
  *(s16x8*)(dst + base + 128) = u1.v;    // lane (lq0+1)*16 + l15
}

__device__ __forceinline__ f32x4 mfma16(s16x8 a, s16x8 b, f32x4 c) {
  asm("v_mfma_f32_16x16x32_bf16 %0, %1, %2, %0" : "+v"(c) : "v"(a), "v"(b));
  return c;
}

__device__ __forceinline__ void gload16(const void* g, void* lds) {
  __builtin_amdgcn_global_load_lds(
      (const __attribute__((address_space(1))) unsigned int*)g,
      (__attribute__((address_space(3))) unsigned int*)lds, 16, 0, 0);
}

// GEMM1 (r21-proven): LDS-free K-loop, pinned distance-3 pipeline, 128x128
// tile, BK=64, 4 waves (2m x 2n). Fragment-order operands; each fragment =
// 1 contiguous 1KB load. Epilogue: relu+bias via LDS C-stage, 16B stores
// into Hp in FRAGMENT order (GEMM2 consumes directly).
__global__ __launch_bounds__(256)
void k_gemm1(const int* __restrict__ hdr,
             const __hip_bfloat16* __restrict__ Ap,
             const __hip_bfloat16* __restrict__ Bp,
             const float* __restrict__ bias,
             __hip_bfloat16* __restrict__ Hout) {
  constexpr int NS = 8, NT = 16, NPH = 2 * NS;
  const int* tb = hdr + 13;
  const int total = tb[4];

  __shared__ __align__(16) char LDS[34816];   // C-stage only (128 x 272B)

  const int idx = blockIdx.x;
  if (idx >= total) return;
  const int qc = total >> 3, rc = total & 7;
  const int xcd = idx & 7;
  const int cbase = (xcd < rc) ? xcd * (qc + 1) : rc * (qc + 1) + (xcd - rc) * qc;
  const int w = cbase + (idx >> 3);

  const int tid = threadIdx.x, lane = tid & 63, wv = tid >> 6;
  const int wm = (wv >> 1) << 6, wn = (wv & 1) << 6;
  const int l15 = lane & 15, lq = lane >> 4;

  int g = 0;
  while (tb[g + 1] <= w) ++g;
  const int local = w - tb[g];
  const int mt = local / NT, nt = local % NT;
  const int cnt = hdr[g];
  int nrows = cnt - (mt << 7);
  nrows = nrows > 128 ? 128 : nrows;

  const int amt = (hdr[13 + g] >> 4) + mt;
  const __hip_bfloat16* aF = Ap + (((size_t)amt * NS) << 13) +
                             (((wv >> 1) << 2) << 9) + lane * 8;
  const __hip_bfloat16* bF = Bp + (((size_t)(g * NT + nt) * NS) << 13) +
                             (((wv & 1) << 2) << 9) + lane * 8;

  f32x4 acc[4][4];
  const f32x4 fz = {0.f, 0.f, 0.f, 0.f};
#pragma unroll
  for (int m = 0; m < 4; ++m)
#pragma unroll
    for (int n = 0; n < 4; ++n) acc[m][n] = fz;

  s16x8 a0[4], b0[4], a1[4], b1[4], a2[4], b2[4], a3[4], b3[4];
  auto LD = [&](int ph, s16x8* a, s16x8* b) {
    const size_t o = (size_t)ph << 12;
#pragma unroll
    for (int i = 0; i < 4; ++i) {
      a[i] = *(const s16x8*)(aF + o + (i << 9));
      b[i] = *(const s16x8*)(bF + o + (i << 9));
    }
  };
  auto MM = [&](s16x8* a, s16x8* b) {
    __builtin_amdgcn_s_setprio(1);
#pragma unroll
    for (int m = 0; m < 4; ++m)
#pragma unroll
      for (int n = 0; n < 4; ++n)
        acc[m][n] = mfma16(a[m], b[n], acc[m][n]);
    __builtin_amdgcn_s_setprio(0);
  };

  LD(0, a0, b0); SB();
  LD(1, a1, b1); SB();
  LD(2, a2, b2); SB();
#pragma unroll
  for (int ph = 0; ph < NPH; ph += 4) {
    if (ph + 3 < NPH) LD(ph + 3, a3, b3);
    SB(); MM(a0, b0); SB();
    if (ph + 4 < NPH) LD(ph + 4, a0, b0);
    SB(); MM(a1, b1); SB();
    if (ph + 5 < NPH) LD(ph + 5, a1, b1);
    SB(); MM(a2, b2); SB();
    if (ph + 6 < NPH) LD(ph + 6, a2, b2);
    SB(); MM(a3, b3); SB();
  }
  asm volatile("s_nop 7\ns_nop 7\ns_nop 7");    // MFMA->VALU hazard guard

  // epilogue (r21-proven): relu+bias via LDS C-stage (stride 272), then 16B
  // stores into Hp in FRAGMENT order.
  const int rq = lq << 2;
#pragma unroll
  for (int n = 0; n < 4; ++n) {
    const int col = wn + (n << 4) + l15;
    const float bv = bias[g * FDIM + (nt << 7) + col];
#pragma unroll
    for (int m = 0; m < 4; ++m)
#pragma unroll
      for (int j = 0; j < 4; ++j) {
        const int row = wm + (m << 4) + rq + j;
        float v = acc[m][n][j] + bv;
        v = v > 0.f ? v : 0.f;
        *(__hip_bfloat16*)(LDS + row * 272 + col * 2) = __float2bfloat16(v);
      }
  }
  __syncthreads();
  const int r = tid >> 1, hf = tid & 1;
  if (r < nrows) {
    const char* src = LDS + r * 272 + hf * 128;   // 64 bf16 for kstep 2nt+hf
    const int hmt = (hdr[18 + g] >> 2) + mt;
    __hip_bfloat16* dblk =
        Hout + (((size_t)hmt * 32 + (nt << 1) + hf) << 13);
    const int rb = r >> 4, l15r = r & 15;
#pragma unroll
    for (int kk2 = 0; kk2 < 2; ++kk2)
#pragma unroll
      for (int lq2 = 0; lq2 < 4; ++lq2) {
        s16x8 v = *(const s16x8*)(src + kk2 * 64 + lq2 * 16);
        *(s16x8*)(dblk +
                  ((((kk2 << 3) + rb) << 6) + (lq2 << 4) + l15r) * 8) = v;
      }
  }
}

// GEMM2: LDS + T4 counted depth-2 (r20-proven schedule) on FRAGMENT-order
// operands. 128x128 tile, BK=64, 4 waves (2m x 2n).
// Staging (linear): thread unit = wv*64+lane, +256 units per instruction ->
// each wave-instruction reads 1KB contiguous; LDS dest = linear same offset.
// Fragment reads: addr = ((kk*8 + rb + m)*64)*16 + lane*16 -- uniform +
// lane*16, fully linear ds_read_b128, no swizzle.
// A = Hp frag order (K=2048, NS=32), B = W2p frag order.
// vmcnt(8) retires exactly the prior step's 8 gloads. fp32 scatter epilogue.
__global__ __launch_bounds__(256, 2)
void k_gemm2(const int* __restrict__ hdr, const int* __restrict__ perm,
             const __hip_bfloat16* __restrict__ Ap,
             const __hip_bfloat16* __restrict__ Bp,
             const float* __restrict__ bias, float* __restrict__ Yout) {
  constexpr int NS = 32, NT = 4;
  const int* tb = hdr + 18;
  const int total = tb[4];

  __shared__ __align__(16) char LDS[65536];
  char* As = LDS;            // + p*16384
  char* Bs = LDS + 32768;    // + p*16384

  const int idx = blockIdx.x;
  if (idx >= total) return;
  const int qc = total >> 3, rc = total & 7;
  const int xcd = idx & 7;
  const int cbase = (xcd < rc) ? xcd * (qc + 1) : rc * (qc + 1) + (xcd - rc) * qc;
  const int w = cbase + (idx >> 3);

  const int tid = threadIdx.x, lane = tid & 63, wv = tid >> 6;
  const int wm = (wv >> 1) << 6, wn = (wv & 1) << 6;
  const int l15 = lane & 15, lq = lane >> 4;

  int g = 0;
  while (tb[g + 1] <= w) ++g;
  const int local = w - tb[g];
  const int mt = local / NT, nt = local % NT;
  const int cnt = hdr[g], off = hdr[8 + g];
  int nrows = cnt - (mt << 7);
  nrows = nrows > 128 ? 128 : nrows;

  const int amt = (hdr[18 + g] >> 2) + mt;
  // linear per-thread staging sources (elements): unit (wv*64+lane)*8
  const __hip_bfloat16* aS = Ap + (((size_t)amt * NS) << 13) +
                             ((wv << 6) + lane) * 8;
  const __hip_bfloat16* bS = Bp + (((size_t)(g * NT + nt) * NS) << 13) +
                             ((wv << 6) + lane) * 8;

  f32x4 acc[4][4];
  const f32x4 fz = {0.f, 0.f, 0.f, 0.f};
#pragma unroll
  for (int m = 0; m < 4; ++m)
#pragma unroll
    for (int n = 0; n < 4; ++n) acc[m][n] = fz;

  auto STAGE = [&](int s, int p) {
    const size_t so = (size_t)s << 13;
    char* Ad = As + (p << 14) + (wv << 10);
    char* Bd = Bs + (p << 14) + (wv << 10);
#pragma unroll
    for (int i = 0; i < 4; ++i) {
      gload16(aS + so + (i << 11), Ad + (i << 12));
      gload16(bS + so + (i << 11), Bd + (i << 12));
    }
  };
  auto COMPUTE = [&](int p) {
    const char* Ab = As + (p << 14);
    const char* Bb = Bs + (p << 14);
#pragma unroll
    for (int kk = 0; kk < 2; ++kk) {
      s16x8 a[4], b[4];
#pragma unroll
      for (int m = 0; m < 4; ++m)
        a[m] = *(const s16x8*)(Ab + (((kk << 3) + (wm >> 4) + m) << 10) +
                               (lane << 4));
#pragma unroll
      for (int n = 0; n < 4; ++n)
        b[n] = *(const s16x8*)(Bb + (((kk << 3) + (wn >> 4) + n) << 10) +
                               (lane << 4));
      __builtin_amdgcn_s_setprio(1);
#pragma unroll
      for (int m = 0; m < 4; ++m)
#pragma unroll
        for (int n = 0; n < 4; ++n)
          acc[m][n] = mfma16(a[m], b[n], acc[m][n]);
      __builtin_amdgcn_s_setprio(0);
    }
  };

  STAGE(0, 0);
  for (int s = 0; s < NS; ++s) {
    const int p = s & 1;
    if (s + 1 < NS) {
      STAGE(s + 1, p ^ 1);
      asm volatile("s_waitcnt vmcnt(8)" ::: "memory");  // step-s retired
    } else {
      asm volatile("s_waitcnt vmcnt(0)" ::: "memory");
    }
    __builtin_amdgcn_s_barrier();
    asm volatile("" ::: "memory");
    COMPUTE(p);
    asm volatile("" ::: "memory");
    __builtin_amdgcn_s_barrier();
    asm volatile("" ::: "memory");
  }
  asm volatile("s_nop 7\ns_nop 7\ns_nop 7");   // MFMA->VALU hazard guard

  const int rq = lq << 2;
#pragma unroll
  for (int n = 0; n < 4; ++n) {
    const int ncol = (nt << 7) + wn + (n << 4) + l15;
    const float bv = bias[g * HDIM + ncol];
#pragma unroll
    for (int m = 0; m < 4; ++m)
#pragma unroll
      for (int j = 0; j < 4; ++j) {
        const int rl = wm + (m << 4) + rq + j;
        if (rl < nrows) {
          const int tok = perm[off + (mt << 7) + rl];
          Yout[((size_t)tok << 9) + ncol] = acc[m][n][j] + bv;
        }
      }
  }
}

extern "C" void kernel_launch(void* const* d_in, const int* in_sizes, int n_in,
                              void* d_out, int out_size, void* d_ws,
                              size_t ws_size, hipStream_t stream) {
  const float* x    = (const float*)d_in[0];
  const int* b_seq  = (const int*)d_in[1];
  const float* W1   = (const float*)d_in[2];
  const float* B1   = (const float*)d_in[3];
  const float* W2   = (const float*)d_in[4];
  const float* B2   = (const float*)d_in[5];
  float* out        = (float*)d_out;

  char* ws = (char*)d_ws;
  int* hdr  = (int*)ws;                          // 1 KB header
  int* perm = (int*)(ws + 1024);                 // 64 KB
  __hip_bfloat16* xa  = (__hip_bfloat16*)(ws + 66560);   // frag order
  __hip_bfloat16* W1p = xa + (size_t)MAXMT * 8 * 8192;   // frag order
  __hip_bfloat16* W2p = W1p + (size_t)NEXP * FDIM * HDIM;// frag order
  __hip_bfloat16* Hp  = W2p + (size_t)NEXP * HDIM * FDIM;// frag order

  const int n4 = NTOK * HDIM / 4;

  k_init<<<1024, 256, 0, stream>>>((const int4*)b_seq, b_seq, (float4*)out,
                                   n4, hdr);
  k_fill<<<NTOK / 256, 256, 0, stream>>>(b_seq, hdr, perm);
  k_pack_a<<<MAXMT * 8, 256, 0, stream>>>(x, hdr, perm, xa);
  k_transpose_both<<<2048, 256, 0, stream>>>(W1, W1p, W2, W2p);
  // grids cover worst-case tile counts; blocks past the actual total exit
  k_gemm1<<<2112, 256, 0, stream>>>(hdr, xa, W1p, B1, Hp);
  k_gemm2<<<528, 256, 0, stream>>>(hdr, perm, Hp, W2p, B2, out);
}

// Round 23
// 115.152 us; speedup vs baseline: 1.1273x; 1.0337x over previous
//
#include <hip/hip_runtime.h>
#include <hip/hip_bf16.h>

// ---------------------------------------------------------------------------
// BehaviorSpecificPFF: token-routed 4-expert FFN.
//   y[tok] = relu(x[tok] @ W1[g] + B1[g]) @ W2[g] + B2[g],  g = b_seq[tok]-1
//   b_seq==0 -> zeros.
// Round 23: r22 GEMMs byte-identical (GEMM1 = pinned distance-3 frag-direct
// + frag-Hp epilogue, ~33us; GEMM2 = LDS+T4 counted depth-2 on frag-order
// operands, ~51.5us = its path floor). Prep: transpose fused INTO k_init
// (independent work, blocks 1024-3071), 6 -> 5 launches.
// ---------------------------------------------------------------------------

typedef short s16x8 __attribute__((ext_vector_type(8)));
typedef float f32x4 __attribute__((ext_vector_type(4)));

#define NTOK   16384
#define HDIM   512
#define FDIM   2048
#define NEXP   4
#define MAXMT  132   // worst-case total 128-row m-tiles (4 experts)
#define SB()   __builtin_amdgcn_sched_barrier(0)

// ---- header layout (ints) in ws ----
// [0..3] counts  [4..7] cursors  [8..12] token offsets ([12]=total)
// [13..17] gemm1 tile bases, mt-base = hdr[13+g]>>4 ([17]=total)
// [18..22] gemm2 tile bases, mt-base = hdr[18+g]>>2

// Fused: out-zeroing + count/scan (blocks 0-1023) and W1/W2 transpose
// (blocks 1024-3071). The two halves touch disjoint data.
__global__ __launch_bounds__(256)
void k_init(const int4* __restrict__ b4, const int* __restrict__ b_seq,
            float4* __restrict__ out, int n4, int* __restrict__ hdr,
            const float* __restrict__ W1, __hip_bfloat16* __restrict__ W1p,
            const float* __restrict__ W2, __hip_bfloat16* __restrict__ W2p) {
  const int t = threadIdx.x;
  if (blockIdx.x >= 1024) {
    // ---- transpose half: both weights to FRAGMENT order ----
    __shared__ float tile[64][69];   // pad 69: conflict-free col reads
    const int tb2 = blockIdx.x - 1024;
    const bool first = tb2 < 1024;
    const int id = first ? tb2 : tb2 - 1024;
    const int R = first ? HDIM : FDIM;
    const int C = first ? FDIM : HDIM;
    const int nbx = C >> 6, nby = R >> 6;
    const int bx = id % nbx, rest = id / nbx;
    const int by = rest % nby, g = rest / nby;
    const float* S = (first ? W1 : W2) + (size_t)g * R * C;
    __hip_bfloat16* dst = first ? W1p : W2p;
    const int c0 = bx << 6, r0 = by << 6;
    const int lr = t >> 4, lc = (t & 15) << 2;
#pragma unroll
    for (int p = 0; p < 4; ++p) {
      float4 v = *(const float4*)(S + (size_t)(r0 + lr + p * 16) * C + c0 + lc);
      float* tr = &tile[lr + p * 16][lc];
      tr[0] = v.x; tr[1] = v.y; tr[2] = v.z; tr[3] = v.w;
    }
    __syncthreads();
    const int c = t >> 2, rq = t & 3;
    union { __hip_bfloat16 b[8]; s16x8 v; } u0, u1;
#pragma unroll
    for (int j = 0; j < 8; ++j) {
      u0.b[j] = __float2bfloat16(tile[rq * 16 + j][c]);
      u1.b[j] = __float2bfloat16(tile[rq * 16 + 8 + j][c]);
    }
    const int rI = c0 + c, kI = r0 + rq * 16;
    const int tl = g * (C >> 7) + (rI >> 7);
    const int ks = kI >> 6, kk = (kI >> 5) & 1, lq0 = (kI >> 3) & 3;
    const int rb = (rI & 127) >> 4;
    const size_t base = (((size_t)tl * (R >> 6) + ks) << 13) +
                        ((((kk << 3) + rb) << 6) + (lq0 << 4) + (rI & 15)) * 8;
    *(s16x8*)(dst + base) = u0.v;          // lane lq0*16 + l15
    *(s16x8*)(dst + base + 128) = u1.v;    // lane (lq0+1)*16 + l15
    return;
  }
  // ---- init half ----
  if (blockIdx.x == 0) {   // fused count+scan
    __shared__ int cnt[4];
    if (t < 4) cnt[t] = 0;
    __syncthreads();
    int c0 = 0, c1 = 0, c2 = 0, c3 = 0;
    for (int i = t; i < NTOK / 4; i += 256) {
      int4 v = b4[i];
      c0 += (v.x == 1) + (v.y == 1) + (v.z == 1) + (v.w == 1);
      c1 += (v.x == 2) + (v.y == 2) + (v.z == 2) + (v.w == 2);
      c2 += (v.x == 3) + (v.y == 3) + (v.z == 3) + (v.w == 3);
      c3 += (v.x == 4) + (v.y == 4) + (v.z == 4) + (v.w == 4);
    }
    if (c0) atomicAdd(&cnt[0], c0);
    if (c1) atomicAdd(&cnt[1], c1);
    if (c2) atomicAdd(&cnt[2], c2);
    if (c3) atomicAdd(&cnt[3], c3);
    __syncthreads();
    if (t == 0) {
      int off = 0, b1 = 0, b2 = 0;
      for (int g = 0; g < 4; ++g) {
        int c = cnt[g];
        hdr[g] = c;
        hdr[8 + g] = off;
        hdr[4 + g] = off;   // cursor
        hdr[13 + g] = b1;
        hdr[18 + g] = b2;
        int mt = (c + 127) >> 7;
        off += c;
        b1 += mt * 16;
        b2 += mt * 4;
      }
      hdr[12] = off; hdr[17] = b1; hdr[22] = b2;
    }
  }
  float4 z; z.x = z.y = z.z = z.w = 0.f;
  for (int i = blockIdx.x * 256 + t; i < n4; i += 1024 * 256) {
    // non-pad out rows are fully rewritten by GEMM2 every call; only padding
    // rows need zeros (out float4-row token = i>>7).
    if (b_seq[i >> 7] == 0) out[i] = z;
  }
}

// LDS-aggregated fill: one global atomic per (block, expert).
__global__ void k_fill(const int* __restrict__ b_seq, int* __restrict__ hdr,
                       int* __restrict__ perm) {
  __shared__ int lcnt[4], base[4];
  const int tid = threadIdx.x;
  if (tid < 4) lcnt[tid] = 0;
  __syncthreads();
  const int i = blockIdx.x * 256 + tid;
  const int g = b_seq[i];
  int r = -1;
  if (g > 0) r = atomicAdd(&lcnt[g - 1], 1);
  __syncthreads();
  if (tid < 4) {
    int c = lcnt[tid];
    base[tid] = c ? atomicAdd(&hdr[4 + tid], c) : 0;
  }
  __syncthreads();
  if (g > 0) perm[base[g - 1] + r] = i;
}

// Gather + convert x into FRAGMENT-ORDER A tiles:
//   xa[mtile][ks][kk][rb][lane]: lane l holds row rb*16+(l&15),
//   k = ks*64 + kk*32 + (l>>4)*8 .. +7 (16B per lane-slot).
// One block per (mtile, ks). OOB rows zero-filled.
__global__ __launch_bounds__(256)
void k_pack_a(const float* __restrict__ x, const int* __restrict__ hdr,
              const int* __restrict__ perm, __hip_bfloat16* __restrict__ xa) {
  const int nmt = hdr[17] >> 4;
  const int b = blockIdx.x >> 3, ks = blockIdx.x & 7;
  if (b >= nmt) return;
  int g = 0;
  while ((hdr[13 + g + 1] >> 4) <= b) ++g;
  const int mt = b - (hdr[13 + g] >> 4);
  const int off = hdr[8 + g], cnt = hdr[g];
  int nrows = cnt - (mt << 7);
  nrows = nrows > 128 ? 128 : nrows;
  const int t = threadIdx.x;
  const int kk = t >> 7, rb = (t >> 4) & 7, l0 = (t & 15) << 2;
  __hip_bfloat16* dst = xa + ((size_t)b << 16) + (ks << 13) +
                        ((((kk << 3) + rb) << 6) + l0) * 8;
#pragma unroll
  for (int i = 0; i < 4; ++i) {
    const int l = l0 + i;
    const int row = (rb << 4) + (l & 15);
    union { __hip_bfloat16 b16[8]; s16x8 v; } u;
    if (row < nrows) {
      const float* src = x + (size_t)perm[off + (mt << 7) + row] * HDIM +
                         (ks << 6) + (kk << 5) + ((l >> 4) << 3);
      float4 v0 = *(const float4*)(src);
      float4 v1 = *(const float4*)(src + 4);
      u.b16[0] = __float2bfloat16(v0.x); u.b16[1] = __float2bfloat16(v0.y);
      u.b16[2] = __float2bfloat16(v0.z); u.b16[3] = __float2bfloat16(v0.w);
      u.b16[4] = __float2bfloat16(v1.x); u.b16[5] = __float2bfloat16(v1.y);
      u.b16[6] = __float2bfloat16(v1.z); u.b16[7] = __float2bfloat16(v1.w);
    } else {
      const s16x8 zz = {0, 0, 0, 0, 0, 0, 0, 0};
      u.v = zz;
    }
    *(s16x8*)(dst + i * 8) = u.v;
  }
}

__device__ __forceinline__ f32x4 mfma16(s16x8 a, s16x8 b, f32x4 c) {
  asm("v_mfma_f32_16x16x32_bf16 %0, %1, %2, %0" : "+v"(c) : "v"(a), "v"(b));
  return c;
}

__device__ __forceinline__ void gload16(const void* g, void* lds) {
  __builtin_amdgcn_global_load_lds(
      (const __attribute__((address_space(1))) unsigned int*)g,
      (__attribute__((address_space(3))) unsigned int*)lds, 16, 0, 0);
}

// GEMM1 (r22-proven): LDS-free K-loop, pinned distance-3 pipeline, 128x128
// tile, BK=64, 4 waves (2m x 2n). Fragment-order operands; each fragment =
// 1 contiguous 1KB load. Epilogue: relu+bias via LDS C-stage, 16B stores
// into Hp in FRAGMENT order (GEMM2 consumes directly).
__global__ __launch_bounds__(256)
void k_gemm1(const int* __restrict__ hdr,
             const __hip_bfloat16* __restrict__ Ap,
             const __hip_bfloat16* __restrict__ Bp,
             const float* __restrict__ bias,
             __hip_bfloat16* __restrict__ Hout) {
  constexpr int NS = 8, NT = 16, NPH = 2 * NS;
  const int* tb = hdr + 13;
  const int total = tb[4];

  __shared__ __align__(16) char LDS[34816];   // C-stage only (128 x 272B)

  const int idx = blockIdx.x;
  if (idx >= total) return;
  const int qc = total >> 3, rc = total & 7;
  const int xcd = idx & 7;
  const int cbase = (xcd < rc) ? xcd * (qc + 1) : rc * (qc + 1) + (xcd - rc) * qc;
  const int w = cbase + (idx >> 3);

  const int tid = threadIdx.x, lane = tid & 63, wv = tid >> 6;
  const int wm = (wv >> 1) << 6, wn = (wv & 1) << 6;
  const int l15 = lane & 15, lq = lane >> 4;

  int g = 0;
  while (tb[g + 1] <= w) ++g;
  const int local = w - tb[g];
  const int mt = local / NT, nt = local % NT;
  const int cnt = hdr[g];
  int nrows = cnt - (mt << 7);
  nrows = nrows > 128 ? 128 : nrows;

  const int amt = (hdr[13 + g] >> 4) + mt;
  const __hip_bfloat16* aF = Ap + (((size_t)amt * NS) << 13) +
                             (((wv >> 1) << 2) << 9) + lane * 8;
  const __hip_bfloat16* bF = Bp + (((size_t)(g * NT + nt) * NS) << 13) +
                             (((wv & 1) << 2) << 9) + lane * 8;

  f32x4 acc[4][4];
  const f32x4 fz = {0.f, 0.f, 0.f, 0.f};
#pragma unroll
  for (int m = 0; m < 4; ++m)
#pragma unroll
    for (int n = 0; n < 4; ++n) acc[m][n] = fz;

  s16x8 a0[4], b0[4], a1[4], b1[4], a2[4], b2[4], a3[4], b3[4];
  auto LD = [&](int ph, s16x8* a, s16x8* b) {
    const size_t o = (size_t)ph << 12;
#pragma unroll
    for (int i = 0; i < 4; ++i) {
      a[i] = *(const s16x8*)(aF + o + (i << 9));
      b[i] = *(const s16x8*)(bF + o + (i << 9));
    }
  };
  auto MM = [&](s16x8* a, s16x8* b) {
    __builtin_amdgcn_s_setprio(1);
#pragma unroll
    for (int m = 0; m < 4; ++m)
#pragma unroll
      for (int n = 0; n < 4; ++n)
        acc[m][n] = mfma16(a[m], b[n], acc[m][n]);
    __builtin_amdgcn_s_setprio(0);
  };

  LD(0, a0, b0); SB();
  LD(1, a1, b1); SB();
  LD(2, a2, b2); SB();
#pragma unroll
  for (int ph = 0; ph < NPH; ph += 4) {
    if (ph + 3 < NPH) LD(ph + 3, a3, b3);
    SB(); MM(a0, b0); SB();
    if (ph + 4 < NPH) LD(ph + 4, a0, b0);
    SB(); MM(a1, b1); SB();
    if (ph + 5 < NPH) LD(ph + 5, a1, b1);
    SB(); MM(a2, b2); SB();
    if (ph + 6 < NPH) LD(ph + 6, a2, b2);
    SB(); MM(a3, b3); SB();
  }
  asm volatile("s_nop 7\ns_nop 7\ns_nop 7");    // MFMA->VALU hazard guard

  // epilogue: relu+bias via LDS C-stage (stride 272), then 16B stores into
  // Hp in FRAGMENT order.
  const int rq = lq << 2;
#pragma unroll
  for (int n = 0; n < 4; ++n) {
    const int col = wn + (n << 4) + l15;
    const float bv = bias[g * FDIM + (nt << 7) + col];
#pragma unroll
    for (int m = 0; m < 4; ++m)
#pragma unroll
      for (int j = 0; j < 4; ++j) {
        const int row = wm + (m << 4) + rq + j;
        float v = acc[m][n][j] + bv;
        v = v > 0.f ? v : 0.f;
        *(__hip_bfloat16*)(LDS + row * 272 + col * 2) = __float2bfloat16(v);
      }
  }
  __syncthreads();
  const int r = tid >> 1, hf = tid & 1;
  if (r < nrows) {
    const char* src = LDS + r * 272 + hf * 128;   // 64 bf16 for kstep 2nt+hf
    const int hmt = (hdr[18 + g] >> 2) + mt;
    __hip_bfloat16* dblk =
        Hout + (((size_t)hmt * 32 + (nt << 1) + hf) << 13);
    const int rb = r >> 4, l15r = r & 15;
#pragma unroll
    for (int kk2 = 0; kk2 < 2; ++kk2)
#pragma unroll
      for (int lq2 = 0; lq2 < 4; ++lq2) {
        s16x8 v = *(const s16x8*)(src + kk2 * 64 + lq2 * 16);
        *(s16x8*)(dblk +
                  ((((kk2 << 3) + rb) << 6) + (lq2 << 4) + l15r) * 8) = v;
      }
  }
}

// GEMM2 (r22-proven): LDS + T4 counted depth-2 on FRAGMENT-order operands.
// 128x128 tile, BK=64, 4 waves (2m x 2n). Linear staging (1KB contiguous
// per wave-instr), linear uniform+lane*16 fragment reads (no swizzle).
// A = Hp frag order (K=2048, NS=32), B = W2p frag order. vmcnt(8).
__global__ __launch_bounds__(256, 2)
void k_gemm2(const int* __restrict__ hdr, const int* __restrict__ perm,
             const __hip_bfloat16* __restrict__ Ap,
             const __hip_bfloat16* __restrict__ Bp,
             const float* __restrict__ bias, float* __restrict__ Yout) {
  constexpr int NS = 32, NT = 4;
  const int* tb = hdr + 18;
  const int total = tb[4];

  __shared__ __align__(16) char LDS[65536];
  char* As = LDS;            // + p*16384
  char* Bs = LDS + 32768;    // + p*16384

  const int idx = blockIdx.x;
  if (idx >= total) return;
  const int qc = total >> 3, rc = total & 7;
  const int xcd = idx & 7;
  const int cbase = (xcd < rc) ? xcd * (qc + 1) : rc * (qc + 1) + (xcd - rc) * qc;
  const int w = cbase + (idx >> 3);

  const int tid = threadIdx.x, lane = tid & 63, wv = tid >> 6;
  const int wm = (wv >> 1) << 6, wn = (wv & 1) << 6;
  const int l15 = lane & 15, lq = lane >> 4;

  int g = 0;
  while (tb[g + 1] <= w) ++g;
  const int local = w - tb[g];
  const int mt = local / NT, nt = local % NT;
  const int cnt = hdr[g], off = hdr[8 + g];
  int nrows = cnt - (mt << 7);
  nrows = nrows > 128 ? 128 : nrows;

  const int amt = (hdr[18 + g] >> 2) + mt;
  // linear per-thread staging sources (elements): unit (wv*64+lane)*8
  const __hip_bfloat16* aS = Ap + (((size_t)amt * NS) << 13) +
                             ((wv << 6) + lane) * 8;
  const __hip_bfloat16* bS = Bp + (((size_t)(g * NT + nt) * NS) << 13) +
                             ((wv << 6) + lane) * 8;

  f32x4 acc[4][4];
  const f32x4 fz = {0.f, 0.f, 0.f, 0.f};
#pragma unroll
  for (int m = 0; m < 4; ++m)
#pragma unroll
    for (int n = 0; n < 4; ++n) acc[m][n] = fz;

  auto STAGE = [&](int s, int p) {
    const size_t so = (size_t)s << 13;
    char* Ad = As + (p << 14) + (wv << 10);
    char* Bd = Bs + (p << 14) + (wv << 10);
#pragma unroll
    for (int i = 0; i < 4; ++i) {
      gload16(aS + so + (i << 11), Ad + (i << 12));
      gload16(bS + so + (i << 11), Bd + (i << 12));
    }
  };
  auto COMPUTE = [&](int p) {
    const char* Ab = As + (p << 14);
    const char* Bb = Bs + (p << 14);
#pragma unroll
    for (int kk = 0; kk < 2; ++kk) {
      s16x8 a[4], b[4];
#pragma unroll
      for (int m = 0; m < 4; ++m)
        a[m] = *(const s16x8*)(Ab + (((kk << 3) + (wm >> 4) + m) << 10) +
                               (lane << 4));
#pragma unroll
      for (int n = 0; n < 4; ++n)
        b[n] = *(const s16x8*)(Bb + (((kk << 3) + (wn >> 4) + n) << 10) +
                               (lane << 4));
      __builtin_amdgcn_s_setprio(1);
#pragma unroll
      for (int m = 0; m < 4; ++m)
#pragma unroll
        for (int n = 0; n < 4; ++n)
          acc[m][n] = mfma16(a[m], b[n], acc[m][n]);
      __builtin_amdgcn_s_setprio(0);
    }
  };

  STAGE(0, 0);
  for (int s = 0; s < NS; ++s) {
    const int p = s & 1;
    if (s + 1 < NS) {
      STAGE(s + 1, p ^ 1);
      asm volatile("s_waitcnt vmcnt(8)" ::: "memory");  // step-s retired
    } else {
      asm volatile("s_waitcnt vmcnt(0)" ::: "memory");
    }
    __builtin_amdgcn_s_barrier();
    asm volatile("" ::: "memory");
    COMPUTE(p);
    asm volatile("" ::: "memory");
    __builtin_amdgcn_s_barrier();
    asm volatile("" ::: "memory");
  }
  asm volatile("s_nop 7\ns_nop 7\ns_nop 7");   // MFMA->VALU hazard guard

  const int rq = lq << 2;
#pragma unroll
  for (int n = 0; n < 4; ++n) {
    const int ncol = (nt << 7) + wn + (n << 4) + l15;
    const float bv = bias[g * HDIM + ncol];
#pragma unroll
    for (int m = 0; m < 4; ++m)
#pragma unroll
      for (int j = 0; j < 4; ++j) {
        const int rl = wm + (m << 4) + rq + j;
        if (rl < nrows) {
          const int tok = perm[off + (mt << 7) + rl];
          Yout[((size_t)tok << 9) + ncol] = acc[m][n][j] + bv;
        }
      }
  }
}

extern "C" void kernel_launch(void* const* d_in, const int* in_sizes, int n_in,
                              void* d_out, int out_size, void* d_ws,
                              size_t ws_size, hipStream_t stream) {
  const float* x    = (const float*)d_in[0];
  const int* b_seq  = (const int*)d_in[1];
  const float* W1   = (const float*)d_in[2];
  const float* B1   = (const float*)d_in[3];
  const float* W2   = (const float*)d_in[4];
  const float* B2   = (const float*)d_in[5];
  float* out        = (float*)d_out;

  char* ws = (char*)d_ws;
  int* hdr  = (int*)ws;                          // 1 KB header
  int* perm = (int*)(ws + 1024);                 // 64 KB
  __hip_bfloat16* xa  = (__hip_bfloat16*)(ws + 66560);   // frag order
  __hip_bfloat16* W1p = xa + (size_t)MAXMT * 8 * 8192;   // frag order
  __hip_bfloat16* W2p = W1p + (size_t)NEXP * FDIM * HDIM;// frag order
  __hip_bfloat16* Hp  = W2p + (size_t)NEXP * HDIM * FDIM;// frag order

  const int n4 = NTOK * HDIM / 4;

  k_init<<<3072, 256, 0, stream>>>((const int4*)b_seq, b_seq, (float4*)out,
                                   n4, hdr, W1, W1p, W2, W2p);
  k_fill<<<NTOK / 256, 256, 0, stream>>>(b_seq, hdr, perm);
  k_pack_a<<<MAXMT * 8, 256, 0, stream>>>(x, hdr, perm, xa);
  // grids cover worst-case tile counts; blocks past the actual total exit
  k_gemm1<<<2112, 256, 0, stream>>>(hdr, xa, W1p, B1, Hp);
  k_gemm2<<<528, 256, 0, stream>>>(hdr, perm, Hp, W2p, B2, out);
}